// Round 10
// baseline (106.521 us; speedup 1.0000x reference)
//
#include <hip/hip_runtime.h>

typedef __bf16 bf16x8 __attribute__((ext_vector_type(8)));
typedef float f32x4 __attribute__((ext_vector_type(4)));

// ---------------------------------------------------------------------------
// Workspace layout (bytes):
#define OFF_BSF   0x000000   // f32  [4][256][1024]  4 MB
#define OFF_BSFT  0x400000   // bf16 [4][1024][256]  2 MB   (spatial-major)
#define OFF_BSFB  0x600000   // bf16 [4][256][1024]  2 MB   (ch-major)
#define OFF_Z     0x800000   // f32  [4][256][1024]  4 MB
#define OFF_SBH   0xC00000   // bf16 [4][256][256]   512 KB  S hi
#define OFF_SBL   0xC80000   // bf16 [4][256][256]   512 KB  S lo (residual)
#define OFF_T0    0xD00000   // bf16 [4][256][256]   T0' = U*S + uv*r^T
#define OFF_UB    0xE80000   // bf16 U = ow*g_w
#define OFF_VB    0xEA0000   // bf16 V = ph_w^T*th_w
#define OFF_UT    0xEC0000   // bf16 U^T
#define OFF_RPART 0xEE0000   // f32 [16][1024] row-sum partials
#define OFF_UV    0xEF1000   // f32 [256]  u = ow*g_b
#define OFF_V2P   0xEF1400   // f32 [4][256]  v2 partials (v2 = ph_w^T*th_b)
#define OFF_W2P   0xEF2400   // f32 [4][256]  w2 partials (w2 = th_w^T*ph_b)
#define OFF_S2    0xEF3400   // f32 s2 = ph_b.th_b
#define OFF_CVEC  0xEF4000   // f32 [4][256]  U*r  (atomic-accumulated)
#define OFF_STATS 0xEF9000   // f32 [4][32][2] RAW (sum, sumsq) via atomics
#define OFF_W2SP  0xEFA000   // f32 [2][4][1024] w2sp partials, ends 0xF02000
#define OFF_YT    0xF10000   // bf16 [4][1024][256]  2 MB  Yt[j][c] = (V.bsf)^T + v2[c]
// ---------------------------------------------------------------------------

// ---------------- prep: weights first, then gather --------------------------
// Round-9 lesson: the direct-fp32 U/V branches ran a 256-ITERATION SERIAL
// k-loop (load g_w[k*256+t] -> 16 FMAs) with no unroll => ~50us latency-bound
// straggler (the exact pattern banned after round 5, reintroduced in round 6;
// it explains both R8's 53us prep and the R6->R8 regression). Fix:
// #pragma unroll 16 => 16 independent coalesced loads in flight (~4us), and
// weight branches moved to blocks 0-57 so they fully overlap the gather.
__global__ __launch_bounds__(256) void prep_k(
    const float* __restrict__ f0, const float* __restrict__ f1,
    const float* __restrict__ f2, const float* __restrict__ f3,
    const float* __restrict__ f4,
    const float* __restrict__ g_w, const float* __restrict__ ph_w,
    const float* __restrict__ th_w, const float* __restrict__ ow_w,
    const float* __restrict__ g_b, const float* __restrict__ ph_b,
    const float* __restrict__ th_b,
    char* __restrict__ ws)
{
  const int blk = blockIdx.x, t = threadIdx.x;
  __shared__ __attribute__((aligned(16))) union {
    __bf16 Lt[16][66];
    float wk[4096];
    float vec2[544];
  } sm;

  if (blk < 16) {
    // ---- U = ow_w . g_w (direct fp32), rows m0..m0+15; writes UB + UT
    const int m0 = blk * 16;
#pragma unroll
    for (int i = 0; i < 16; ++i) {
      int lin = t + i * 256;
      int row = lin >> 8, k = lin & 255;
      sm.wk[row * 256 + k] = ow_w[(size_t)(m0 + row) * 256 + k];
    }
    __syncthreads();
    float acc[16];
#pragma unroll
    for (int mi = 0; mi < 16; ++mi) acc[mi] = 0.f;
#pragma unroll 16
    for (int k = 0; k < 256; ++k) {
      float gv = g_w[(size_t)k * 256 + t];
#pragma unroll
      for (int mi = 0; mi < 16; ++mi) acc[mi] += sm.wk[mi * 256 + k] * gv;
    }
    __bf16* ub = (__bf16*)(ws + OFF_UB);
    __bf16* ut = (__bf16*)(ws + OFF_UT);
#pragma unroll
    for (int mi = 0; mi < 16; ++mi)
      ub[(size_t)(m0 + mi) * 256 + t] = (__bf16)acc[mi];
    bf16x8 o0, o1;
#pragma unroll
    for (int j = 0; j < 8; ++j) { o0[j] = (__bf16)acc[j]; o1[j] = (__bf16)acc[8 + j]; }
    *(bf16x8*)&ut[(size_t)t * 256 + m0]     = o0;
    *(bf16x8*)&ut[(size_t)t * 256 + m0 + 8] = o1;
  } else if (blk < 32) {
    // ---- V = ph_w^T . th_w (direct fp32), rows m0..m0+15
    const int m0 = (blk - 16) * 16;
#pragma unroll
    for (int i = 0; i < 16; ++i) {
      int lin = t + i * 256;
      int k = lin >> 4, mi = lin & 15;
      sm.wk[k * 16 + mi] = ph_w[(size_t)k * 256 + m0 + mi];
    }
    __syncthreads();
    float acc[16];
#pragma unroll
    for (int mi = 0; mi < 16; ++mi) acc[mi] = 0.f;
#pragma unroll 16
    for (int k = 0; k < 256; ++k) {
      float tv = th_w[(size_t)k * 256 + t];
#pragma unroll
      for (int mi = 0; mi < 16; ++mi) acc[mi] += sm.wk[k * 16 + mi] * tv;
    }
    __bf16* vb = (__bf16*)(ws + OFF_VB);
#pragma unroll
    for (int mi = 0; mi < 16; ++mi)
      vb[(size_t)(m0 + mi) * 256 + t] = (__bf16)acc[mi];
  } else if (blk < 48) {
    // ---- uv = ow_w . g_b : 16 blocks x 16 rows, LDS tile reduction
    const int r0 = (blk - 32) * 16;
    float* uv = (float*)(ws + OFF_UV);
    sm.vec2[t] = g_b[t];
    __syncthreads();
    const int rl = t >> 4;             // 0..15 local row
    const int ci = (t & 15) * 16;      // column chunk start
    const float* p = ow_w + (size_t)(r0 + rl) * 256 + ci;
    float acc = 0.f;
#pragma unroll
    for (int u = 0; u < 4; ++u) {
      float4 v = *(const float4*)(p + u * 4);
      acc += v.x * sm.vec2[ci + u * 4]     + v.y * sm.vec2[ci + u * 4 + 1]
           + v.z * sm.vec2[ci + u * 4 + 2] + v.w * sm.vec2[ci + u * 4 + 3];
    }
    __syncthreads();
    sm.vec2[256 + rl * 17 + (t & 15)] = acc;
    __syncthreads();
    if (t < 16) {
      float s = 0.f;
#pragma unroll
      for (int i = 0; i < 16; ++i) s += sm.vec2[256 + t * 17 + i];
      uv[r0 + t] = s;
    }
  } else if (blk < 52) {
    // ---- v2 partials: v2part[q][t] = sum_{c in chunk q} ph_w[c][t]*th_b[c]
    const int q = blk - 48, c0 = q * 64;
    float* v2p = (float*)(ws + OFF_V2P);
    if (t < 64) sm.vec2[t] = th_b[c0 + t];
    __syncthreads();
    float acc = 0.f;
#pragma unroll 16
    for (int c = 0; c < 64; ++c)
      acc += ph_w[(size_t)(c0 + c) * 256 + t] * sm.vec2[c];
    v2p[q * 256 + t] = acc;
  } else if (blk < 56) {
    // ---- w2 partials: w2part[q][t] = sum_{c in chunk q} th_w[c][t]*ph_b[c]
    const int q = blk - 52, c0 = q * 64;
    float* w2p = (float*)(ws + OFF_W2P);
    if (t < 64) sm.vec2[t] = ph_b[c0 + t];
    __syncthreads();
    float acc = 0.f;
#pragma unroll 16
    for (int c = 0; c < 64; ++c)
      acc += th_w[(size_t)(c0 + c) * 256 + t] * sm.vec2[c];
    w2p[q * 256 + t] = acc;
  } else if (blk == 56) {
    // ---- s2 = ph_b.th_b ; zero raw GN stats
    float* s2 = (float*)(ws + OFF_S2);
    if (t < 64) {
      float pa = ph_b[t] * th_b[t] + ph_b[64 + t] * th_b[64 + t]
               + ph_b[128 + t] * th_b[128 + t] + ph_b[192 + t] * th_b[192 + t];
#pragma unroll
      for (int off = 32; off; off >>= 1) pa += __shfl_down(pa, off);
      if (t == 0) s2[0] = pa;
    }
    ((float*)(ws + OFF_STATS))[t] = 0.f;
  } else if (blk == 57) {
    // ---- zero cvec accumulator
    float* cvec = (float*)(ws + OFF_CVEC);
#pragma unroll
    for (int i = 0; i < 4; ++i) cvec[i * 256 + t] = 0.f;
  } else {
    // ---- gather: 16 channels x 64 spatial per block (1024 blocks)
    const int g = blk - 58;
    float*  bsf   = (float*)(ws + OFF_BSF);
    __bf16* bsfT  = (__bf16*)(ws + OFF_BSFT);
    __bf16* bsfB  = (__bf16*)(ws + OFF_BSFB);
    float*  rpart = (float*)(ws + OFF_RPART);
    const int sblk = g & 15, cgrp = (g >> 4) & 15, b = g >> 8;
    const int c0 = cgrp * 16, s0 = sblk * 64;
    const int spl = t & 63, sp = s0 + spl;
    const int y = sp >> 5, x = sp & 31;
#pragma unroll
    for (int i = 0; i < 4; ++i) {
      const int cl = (t >> 6) + i * 4;           // 0..15
      const int nc = b * 256 + c0 + cl;

      const float* p0 = f0 + (size_t)nc * 16384 + (y * 4) * 128 + x * 4;
      float4 r0 = *(const float4*)(p0);
      float4 r1 = *(const float4*)(p0 + 128);
      float4 r2 = *(const float4*)(p0 + 256);
      float4 r3 = *(const float4*)(p0 + 384);
      float a  = fmaxf(fmaxf(r0.x, r0.y), fmaxf(r0.z, r0.w));
      float bb = fmaxf(fmaxf(r1.x, r1.y), fmaxf(r1.z, r1.w));
      float c  = fmaxf(fmaxf(r2.x, r2.y), fmaxf(r2.z, r2.w));
      float d  = fmaxf(fmaxf(r3.x, r3.y), fmaxf(r3.z, r3.w));
      float m0v = fmaxf(fmaxf(a, bb), fmaxf(c, d));

      const float* p1 = f1 + (size_t)nc * 4096 + (y * 2) * 64 + x * 2;
      float2 s0v = *(const float2*)(p1);
      float2 s1v = *(const float2*)(p1 + 64);
      float m1v = fmaxf(fmaxf(s0v.x, s0v.y), fmaxf(s1v.x, s1v.y));

      float v2 = f2[(size_t)nc * 1024 + sp];
      float v3 = f3[(size_t)nc * 256 + (y >> 1) * 16 + (x >> 1)];
      float v4 = f4[(size_t)nc * 64  + (y >> 2) * 8  + (x >> 2)];
      float val = (m0v + m1v + v2 + v3 + v4) * 0.2f;
      bsf[(size_t)nc * 1024 + sp]  = val;
      bsfB[(size_t)nc * 1024 + sp] = (__bf16)val;
      sm.Lt[cl][spl] = (__bf16)val;
      float rs = val;
#pragma unroll
      for (int off = 32; off; off >>= 1) rs += __shfl_down(rs, off);
      if (spl == 0) rpart[sblk * 1024 + nc] = rs;
    }
    __syncthreads();
#pragma unroll
    for (int i = 0; i < 4; ++i) {
      int linear = t + i * 256;                  // 0..1023
      int spl2 = linear >> 4, cl2 = linear & 15;
      bsfT[((size_t)b * 1024 + s0 + spl2) * 256 + c0 + cl2] = sm.Lt[cl2][spl2];
    }
  }
}

// ---------------- GEMM accumulate core (64x64 tile, 4 waves, dbuf) ----------
__device__ __forceinline__ void gemm_acc(
    const __bf16* __restrict__ A, const __bf16* __restrict__ B,
    const int K, const int m0, const int n0,
    __bf16 (*Al)[64][72], __bf16 (*Bl)[64][72],
    f32x4 acc[2][2])
{
  const int t = threadIdx.x;
  const int lane = t & 63, wv = t >> 6;
  const int wm = (wv & 1) * 32, wn = (wv >> 1) * 32;
  const int fr = lane & 15, lk = (lane >> 4) * 8;
  const int sr = t >> 2, sk = (t & 3) * 16;

  const __bf16* Ar = A + (size_t)(m0 + sr) * K + sk;
  const __bf16* Br = B + (size_t)(n0 + sr) * K + sk;

  bf16x8 ra0 = *(const bf16x8*)(Ar);
  bf16x8 ra1 = *(const bf16x8*)(Ar + 8);
  bf16x8 rb0 = *(const bf16x8*)(Br);
  bf16x8 rb1 = *(const bf16x8*)(Br + 8);

  const int nIter = K >> 6;
  int p = 0;
  for (int it = 0; it < nIter; ++it) {
    *(bf16x8*)&Al[p][sr][sk]     = ra0;
    *(bf16x8*)&Al[p][sr][sk + 8] = ra1;
    *(bf16x8*)&Bl[p][sr][sk]     = rb0;
    *(bf16x8*)&Bl[p][sr][sk + 8] = rb1;
    __syncthreads();
    if (it + 1 < nIter) {
      const __bf16* An = Ar + (size_t)(it + 1) * 64;
      const __bf16* Bn = Br + (size_t)(it + 1) * 64;
      ra0 = *(const bf16x8*)(An);
      ra1 = *(const bf16x8*)(An + 8);
      rb0 = *(const bf16x8*)(Bn);
      rb1 = *(const bf16x8*)(Bn + 8);
    }
#pragma unroll
    for (int kk = 0; kk < 64; kk += 32) {
      bf16x8 a0 = *(const bf16x8*)&Al[p][wm + fr][kk + lk];
      bf16x8 a1 = *(const bf16x8*)&Al[p][wm + 16 + fr][kk + lk];
      bf16x8 b0 = *(const bf16x8*)&Bl[p][wn + fr][kk + lk];
      bf16x8 b1 = *(const bf16x8*)&Bl[p][wn + 16 + fr][kk + lk];
      acc[0][0] = __builtin_amdgcn_mfma_f32_16x16x32_bf16(a0, b0, acc[0][0], 0, 0, 0);
      acc[0][1] = __builtin_amdgcn_mfma_f32_16x16x32_bf16(a0, b1, acc[0][1], 0, 0, 0);
      acc[1][0] = __builtin_amdgcn_mfma_f32_16x16x32_bf16(a1, b0, acc[1][0], 0, 0, 0);
      acc[1][1] = __builtin_amdgcn_mfma_f32_16x16x32_bf16(a1, b1, acc[1][1], 0, 0, 0);
    }
    __syncthreads();
    p ^= 1;
  }
}

#define ZERO_ACC(acc) \
  _Pragma("unroll") for (int i_ = 0; i_ < 2; ++i_) \
  _Pragma("unroll") for (int j_ = 0; j_ < 2; ++j_) \
    acc[i_][j_] = (f32x4){0.f, 0.f, 0.f, 0.f};

// ---------------- P0: S hi/lo ; Yt(+v2) ; w2sp ; cvec -----------------------
__global__ __launch_bounds__(256) void p0_k(char* __restrict__ ws)
{
  const int blk = blockIdx.x, t = threadIdx.x;
  __shared__ __attribute__((aligned(16))) __bf16 Al[2][64][72];
  __shared__ __attribute__((aligned(16))) __bf16 Bl[2][64][72];
  float* shf = (float*)(&Al[0][0][0]);

  const int lane = t & 63, wv = t >> 6;
  const int wm = (wv & 1) * 32, wn = (wv >> 1) * 32;
  const int fr = lane & 15, rbase = (lane >> 4) * 4;
  (void)lane; (void)wv;

  const __bf16* bsfB = (const __bf16*)(ws + OFF_BSFB);
  const float* rpart = (const float*)(ws + OFF_RPART);

  if (blk < 64) {
    // S = bsfB . bsfB^T (hi/lo bf16)
    const int b = blk >> 4, tl = blk & 15;
    const int m0 = (tl >> 2) * 64, n0 = (tl & 3) * 64;
    f32x4 acc[2][2]; ZERO_ACC(acc);
    gemm_acc(bsfB + (size_t)b * 262144, bsfB + (size_t)b * 262144,
             1024, m0, n0, Al, Bl, acc);
    __bf16* oh = (__bf16*)(ws + OFF_SBH) + (size_t)b * 65536;
    __bf16* ol = (__bf16*)(ws + OFF_SBL) + (size_t)b * 65536;
#pragma unroll
    for (int i = 0; i < 2; ++i)
#pragma unroll
      for (int r = 0; r < 4; ++r) {
        int m = m0 + wm + i * 16 + rbase + r;
#pragma unroll
        for (int j = 0; j < 2; ++j) {
          int n = n0 + wn + j * 16 + fr;
          float v = acc[i][j][r];
          __bf16 h = (__bf16)v;
          oh[(size_t)m * 256 + n] = h;
          ol[(size_t)m * 256 + n] = (__bf16)(v - (float)h);
        }
      }
  } else if (blk < 320) {
    // Yt'[j][c] = sum_c' bsfT[j][c'] * V[c][c']  + v2[c]
    const int q = blk - 64;
    const int b = q >> 6, tl = q & 63;
    const int m0 = (tl >> 2) * 64, n0 = (tl & 3) * 64;   // m: spatial, n: chan
    f32x4 acc[2][2]; ZERO_ACC(acc);
    gemm_acc((const __bf16*)(ws + OFF_BSFT) + (size_t)b * 262144,
             (const __bf16*)(ws + OFF_VB), 256, m0, n0, Al, Bl, acc);
    const float* v2p = (const float*)(ws + OFF_V2P);
    shf[t] = v2p[t] + v2p[256 + t] + v2p[512 + t] + v2p[768 + t];
    __syncthreads();
    __bf16* od = (__bf16*)(ws + OFF_YT) + (size_t)b * 262144;
#pragma unroll
    for (int i = 0; i < 2; ++i)
#pragma unroll
      for (int r = 0; r < 4; ++r) {
        int m = m0 + wm + i * 16 + rbase + r;
#pragma unroll
        for (int j = 0; j < 2; ++j) {
          int n = n0 + wn + j * 16 + fr;
          od[(size_t)m * 256 + n] = (__bf16)(acc[i][j][r] + shf[n]);
        }
      }
  } else if (blk < 352) {
    // w2sp partials: w2spP[half][b][j] = sum_{c in half} w2[c]*bsf[b][c][j]
    const int q = blk - 320;             // 0..31
    const int half = q >> 4, idx = q & 15;
    const int b = idx >> 2, seg = (idx & 3) * 256;
    const int ch0 = half * 128;
    const float* w2p = (const float*)(ws + OFF_W2P);
    const float* bsf = (const float*)(ws + OFF_BSF);
    float* w2sp = (float*)(ws + OFF_W2SP);
    if (t < 128) {
      int c = ch0 + t;
      shf[t] = w2p[c] + w2p[256 + c] + w2p[512 + c] + w2p[768 + c];
    }
    __syncthreads();
    float acc = 0.f;
#pragma unroll 16
    for (int c = 0; c < 128; ++c)
      acc += shf[c] * bsf[((size_t)(b * 256 + ch0 + c)) * 1024 + seg + t];
    w2sp[half * 4096 + b * 1024 + seg + t] = acc;
  } else {
    // cvec[b] += UT-chunk^T . r[b]-chunk   (r inlined from rpart)
    const int q = blk - 352;             // 0..15
    const int b = q >> 2, cc = (q & 3) * 64;
    const __bf16* UT = (const __bf16*)(ws + OFF_UT);
    float* cvec = (float*)(ws + OFF_CVEC);
    if (t < 64) {
      float s = 0.f;
#pragma unroll
      for (int k = 0; k < 16; ++k) s += rpart[k * 1024 + b * 256 + cc + t];
      shf[t] = s;
    }
    __syncthreads();
    float acc = 0.f;
#pragma unroll 16
    for (int c = 0; c < 64; ++c)
      acc += (float)UT[(size_t)(cc + c) * 256 + t] * shf[c];
    atomicAdd(&cvec[b * 256 + t], acc);
  }
}

// ---------------- P1: T0' = U*(Shi+Slo) + uv.r^T  (r inlined) ---------------
__global__ __launch_bounds__(256) void p1_k(char* __restrict__ ws)
{
  const int blk = blockIdx.x, t = threadIdx.x;
  __shared__ __attribute__((aligned(16))) __bf16 Al[2][64][72];
  __shared__ __attribute__((aligned(16))) __bf16 Bl[2][64][72];
  float* shf = (float*)(&Al[0][0][0]);

  const int lane = t & 63, wv = t >> 6;
  const int wm = (wv & 1) * 32, wn = (wv >> 1) * 32;
  const int fr = lane & 15, rbase = (lane >> 4) * 4;
  (void)lane; (void)wv;

  const __bf16* UB = (const __bf16*)(ws + OFF_UB);
  const float* uv  = (const float*)(ws + OFF_UV);
  const float* rpart = (const float*)(ws + OFF_RPART);

  const int b = blk >> 4, tl = blk & 15;
  const int m0 = (tl >> 2) * 64, n0 = (tl & 3) * 64;
  f32x4 acc[2][2]; ZERO_ACC(acc);
  gemm_acc(UB, (const __bf16*)(ws + OFF_SBH) + (size_t)b * 65536,
           256, m0, n0, Al, Bl, acc);
  gemm_acc(UB, (const __bf16*)(ws + OFF_SBL) + (size_t)b * 65536,
           256, m0, n0, Al, Bl, acc);
  float s = 0.f;
#pragma unroll
  for (int k = 0; k < 16; ++k) s += rpart[k * 1024 + b * 256 + t];
  shf[t] = s;
  __syncthreads();
  __bf16* od = (__bf16*)(ws + OFF_T0) + (size_t)b * 65536;
#pragma unroll
  for (int i = 0; i < 2; ++i)
#pragma unroll
    for (int r = 0; r < 4; ++r) {
      int m = m0 + wm + i * 16 + rbase + r;
      float uvm = uv[m];
#pragma unroll
      for (int j = 0; j < 2; ++j) {
        int n = n0 + wn + j * 16 + fr;
        od[(size_t)m * 256 + n] = (__bf16)(acc[i][j][r] + uvm * shf[n]);
      }
    }
}

// ---------------- P2: z = T0'*Yt'^T/N + coef*w2sp + s2*coef + ow_b ----------
__global__ __launch_bounds__(256) void p2_k(char* __restrict__ ws,
                                            const float* __restrict__ ow_b)
{
  const int blk = blockIdx.x, t = threadIdx.x;
  __shared__ __attribute__((aligned(16))) __bf16 Al[2][64][72];
  __shared__ __attribute__((aligned(16))) __bf16 Bl[2][64][72];
  float* shf = (float*)(&Al[0][0][0]);

  const int lane = t & 63, wv = t >> 6;
  const int wm = (wv & 1) * 32, wn = (wv >> 1) * 32;
  const int fr = lane & 15, rbase = (lane >> 4) * 4;

  const int b = blk >> 6, t6 = blk & 63;
  const int mt = t6 >> 4, nt = t6 & 15;
  const int m0 = mt * 64, n0 = nt * 64;
  (void)nt;

  f32x4 acc[2][2]; ZERO_ACC(acc);
  gemm_acc((const __bf16*)(ws + OFF_T0) + (size_t)b * 65536,
           (const __bf16*)(ws + OFF_YT) + (size_t)b * 262144,
           256, m0, n0, Al, Bl, acc);

  const float* uv   = (const float*)(ws + OFF_UV);
  const float* cvec = (const float*)(ws + OFF_CVEC);
  const float* w2sp = (const float*)(ws + OFF_W2SP);
  const float s2v   = *(const float*)(ws + OFF_S2);
  float* SRAW = (float*)(ws + OFF_STATS);
  float* zb = (float*)(ws + OFF_Z) + (size_t)b * 262144;

  float gs[2] = {0.f, 0.f}, gq[2] = {0.f, 0.f};
  int gidx[2];
  const float s1024 = 1.f / 1024.f;
#pragma unroll
  for (int i = 0; i < 2; ++i) {
    gidx[i] = (wm + i * 16 + rbase) >> 3;
#pragma unroll
    for (int r = 0; r < 4; ++r) {
      int m = m0 + wm + i * 16 + rbase + r;
      float coefm = uv[m] + cvec[b * 256 + m] * s1024;
      float qm = s2v * coefm + ow_b[m];
#pragma unroll
      for (int j = 0; j < 2; ++j) {
        int n = n0 + wn + j * 16 + fr;
        float w2n = w2sp[b * 1024 + n] + w2sp[4096 + b * 1024 + n];
        float v = acc[i][j][r] * s1024 + coefm * w2n + qm;
        zb[(size_t)m * 1024 + n] = v;
        gs[i] += v;
        gq[i] += v * v;
      }
    }
  }
  __syncthreads();
  if (t < 16) shf[t] = 0.f;
  __syncthreads();
#pragma unroll
  for (int i = 0; i < 2; ++i) {
    atomicAdd(&shf[gidx[i] * 2], gs[i]);
    atomicAdd(&shf[gidx[i] * 2 + 1], gq[i]);
  }
  __syncthreads();
  if (t < 16) {
    int g = mt * 8 + (t >> 1);
    atomicAdd(&SRAW[(b * 32 + g) * 2 + (t & 1)], shf[t]);
  }
}

// ---------------- fused GN + residual scatter (float4) ----------------------
__device__ __forceinline__ float4 gmix(float4 bz, float4 zz, float a, float c)
{
  float4 r;
  r.x = bz.x + zz.x * a + c;
  r.y = bz.y + zz.y * a + c;
  r.z = bz.z + zz.z * a + c;
  r.w = bz.w + zz.w * a + c;
  return r;
}
__device__ __forceinline__ float max4(float4 v)
{ return fmaxf(fmaxf(v.x, v.y), fmaxf(v.z, v.w)); }

// raw (sum, sumsq) -> (a = inv*gamma, c0 = beta - mean*a)
__device__ __forceinline__ void gn_coeff(const float2* __restrict__ ST,
                                         const float* __restrict__ gamma,
                                         const float* __restrict__ beta,
                                         int b, int ch, float& a, float& c0)
{
  float2 sq = ST[b * 32 + (ch >> 3)];
  float mean = sq.x * (1.0f / 8192.0f);
  float var  = sq.y * (1.0f / 8192.0f) - mean * mean;
  float inv  = rsqrtf(var + 1e-5f);
  a  = inv * gamma[ch];
  c0 = beta[ch] - mean * a;
}

__global__ __launch_bounds__(256) void scat_k(
    const char* __restrict__ ws,
    const float* __restrict__ f0, const float* __restrict__ f1,
    const float* __restrict__ f2, const float* __restrict__ f3,
    const float* __restrict__ f4,
    const float* __restrict__ gamma, const float* __restrict__ beta,
    float* __restrict__ out)
{
  const float* Z = (const float*)(ws + OFF_Z);
  const float* BSF = (const float*)(ws + OFF_BSF);
  const float2* ST = (const float2*)(ws + OFF_STATS);
  const int i4 = blockIdx.x * 256 + threadIdx.x;

  if (i4 < 4194304) {                       // f0: 128x128, upsample x4
    const int l = i4 << 2;
    const int x = l & 127, yy = (l >> 7) & 127, nc = l >> 14;
    const int ch = nc & 255, b = nc >> 8;
    float a, c0; gn_coeff(ST, gamma, beta, b, ch, a, c0);
    size_t base = (size_t)nc * 1024 + ((yy >> 2) << 5) + (x >> 2);
    float v = BSF[base] + Z[base] * a + c0;
    float4 f = ((const float4*)f0)[i4];
    float4 o; o.x = f.x + v; o.y = f.y + v; o.z = f.z + v; o.w = f.w + v;
    ((float4*)out)[i4] = o;
  } else if (i4 < 5242880) {                // f1: 64x64, upsample x2
    const int l4 = i4 - 4194304;
    const int l = l4 << 2;
    const int x = l & 63, yy = (l >> 6) & 63, nc = l >> 12;
    const int ch = nc & 255, b = nc >> 8;
    float a, c0; gn_coeff(ST, gamma, beta, b, ch, a, c0);
    size_t base = (size_t)nc * 1024 + ((yy >> 1) << 5) + (x >> 1);
    float v0 = BSF[base] + Z[base] * a + c0;
    float v1 = BSF[base + 1] + Z[base + 1] * a + c0;
    float4 f = ((const float4*)f1)[l4];
    float4 o; o.x = f.x + v0; o.y = f.y + v0; o.z = f.z + v1; o.w = f.w + v1;
    ((float4*)out)[i4] = o;
  } else if (i4 < 5505024) {                // f2: 32x32, identity
    const int l4 = i4 - 5242880;
    const int l = l4 << 2;
    const int nc = l >> 10, e = l & 1023;
    const int ch = nc & 255, b = nc >> 8;
    float a, c0; gn_coeff(ST, gamma, beta, b, ch, a, c0);
    size_t base = (size_t)nc * 1024 + e;
    float4 z4 = *(const float4*)&Z[base];
    float4 b4 = *(const float4*)&BSF[base];
    float4 v = gmix(b4, z4, a, c0);
    float4 f = ((const float4*)f2)[l4];
    float4 o; o.x = f.x + v.x; o.y = f.y + v.y; o.z = f.z + v.z; o.w = f.w + v.w;
    ((float4*)out)[i4] = o;
  } else if (i4 < 5570560) {                // f3: 16x16, maxpool 2x2
    const int l4 = i4 - 5505024;
    const int l = l4 << 2;
    const int x = l & 15, yy = (l >> 4) & 15, nc = l >> 8;
    const int ch = nc & 255, b = nc >> 8;
    float a, c0; gn_coeff(ST, gamma, beta, b, ch, a, c0);
    size_t base = (size_t)nc * 1024;
    const int p0 = (yy * 2) * 32 + (x * 2);
    float4 r0a = gmix(*(const float4*)&BSF[base + p0],      *(const float4*)&Z[base + p0],      a, c0);
    float4 r0b = gmix(*(const float4*)&BSF[base + p0 + 4],  *(const float4*)&Z[base + p0 + 4],  a, c0);
    float4 r1a = gmix(*(const float4*)&BSF[base + p0 + 32], *(const float4*)&Z[base + p0 + 32], a, c0);
    float4 r1b = gmix(*(const float4*)&BSF[base + p0 + 36], *(const float4*)&Z[base + p0 + 36], a, c0);
    float4 f = ((const float4*)f3)[l4];
    float4 o;
    o.x = f.x + fmaxf(fmaxf(r0a.x, r0a.y), fmaxf(r1a.x, r1a.y));
    o.y = f.y + fmaxf(fmaxf(r0a.z, r0a.w), fmaxf(r1a.z, r1a.w));
    o.z = f.z + fmaxf(fmaxf(r0b.x, r0b.y), fmaxf(r1b.x, r1b.y));
    o.w = f.w + fmaxf(fmaxf(r0b.z, r0b.w), fmaxf(r1b.z, r1b.w));
    ((float4*)out)[i4] = o;
  } else {                                   // f4: 8x8, maxpool 4x4
    const int l4 = i4 - 5570560;
    const int l = l4 << 2;
    const int x = l & 7, yy = (l >> 3) & 7, nc = l >> 6;
    const int ch = nc & 255, b = nc >> 8;
    float a, c0; gn_coeff(ST, gamma, beta, b, ch, a, c0);
    size_t base = (size_t)nc * 1024;
    float4 mx = {-3.4e38f, -3.4e38f, -3.4e38f, -3.4e38f};
#pragma unroll
    for (int r = 0; r < 4; ++r) {
      const float* zp = &Z[base + (size_t)(yy * 4 + r) * 32 + x * 4];
      const float* bp = &BSF[base + (size_t)(yy * 4 + r) * 32 + x * 4];
      float4 q0 = gmix(*(const float4*)(bp),      *(const float4*)(zp),      a, c0);
      float4 q1 = gmix(*(const float4*)(bp + 4),  *(const float4*)(zp + 4),  a, c0);
      float4 q2 = gmix(*(const float4*)(bp + 8),  *(const float4*)(zp + 8),  a, c0);
      float4 q3 = gmix(*(const float4*)(bp + 12), *(const float4*)(zp + 12), a, c0);
      mx.x = fmaxf(mx.x, max4(q0));
      mx.y = fmaxf(mx.y, max4(q1));
      mx.z = fmaxf(mx.z, max4(q2));
      mx.w = fmaxf(mx.w, max4(q3));
    }
    float4 f = ((const float4*)f4)[l4];
    float4 o; o.x = f.x + mx.x; o.y = f.y + mx.y; o.z = f.z + mx.z; o.w = f.w + mx.w;
    ((float4*)out)[i4] = o;
  }
}

// ---------------------------------------------------------------------------
extern "C" void kernel_launch(void* const* d_in, const int* in_sizes, int n_in,
                              void* d_out, int out_size, void* d_ws, size_t ws_size,
                              hipStream_t stream)
{
  (void)in_sizes; (void)n_in; (void)out_size; (void)ws_size;
  const float* f0   = (const float*)d_in[0];
  const float* f1   = (const float*)d_in[1];
  const float* f2   = (const float*)d_in[2];
  const float* f3   = (const float*)d_in[3];
  const float* f4   = (const float*)d_in[4];
  const float* g_w  = (const float*)d_in[5];
  const float* g_b  = (const float*)d_in[6];
  const float* th_w = (const float*)d_in[7];
  const float* th_b = (const float*)d_in[8];
  const float* ph_w = (const float*)d_in[9];
  const float* ph_b = (const float*)d_in[10];
  const float* ow_w = (const float*)d_in[11];
  const float* ow_b = (const float*)d_in[12];
  const float* gn_g = (const float*)d_in[13];
  const float* gn_b = (const float*)d_in[14];
  char* ws = (char*)d_ws;

  // 1) weights (blocks 0-57, unrolled k-loops) + gather (blocks 58-1081)
  prep_k<<<1082, 256, 0, stream>>>(f0, f1, f2, f3, f4,
                                   g_w, ph_w, th_w, ow_w,
                                   g_b, ph_b, th_b, ws);
  // 2) S (hi/lo) ; Yt(+v2) ; w2sp ; cvec
  p0_k<<<368, 256, 0, stream>>>(ws);
  // 3) T0'
  p1_k<<<64, 256, 0, stream>>>(ws);
  // 4) z + GN raw stats
  p2_k<<<256, 256, 0, stream>>>(ws, ow_b);
  // 5) fused GN-normalize + residual scatter
  scat_k<<<21824, 256, 0, stream>>>(ws, f0, f1, f2, f3, f4, gn_g, gn_b,
                                    (float*)d_out);
}

// Round 11
// 85.361 us; speedup vs baseline: 1.2479x; 1.2479x over previous
//
#include <hip/hip_runtime.h>

typedef __bf16 bf16x8 __attribute__((ext_vector_type(8)));
typedef float f32x4 __attribute__((ext_vector_type(4)));

// ---------------------------------------------------------------------------
// Workspace layout (bytes):
#define OFF_BSF   0x000000   // f32  [4][256][1024]  4 MB
#define OFF_BSFT  0x400000   // bf16 [4][1024][256]  2 MB   (spatial-major)
#define OFF_BSFB  0x600000   // bf16 [4][256][1024]  2 MB   (ch-major; reused as Yt in P1+)
#define OFF_YT    0x600000   // bf16 [4][1024][256]  2 MB   Yt[j][c] = (V.bsf)^T + v2[c]
#define OFF_Z     0x800000   // f32  [4][256][1024]  4 MB
#define OFF_SBH   0xC00000   // bf16 [4][256][256]   512 KB  S hi
#define OFF_SBL   0xC80000   // bf16 [4][256][256]   512 KB  S lo (residual)
#define OFF_T0    0xD00000   // bf16 [4][256][256]   T0' = U*S + uv*r^T
#define OFF_OWB   0xE00000   // bf16 [256][256]
#define OFF_GWT   0xE20000   // bf16 g_w^T
#define OFF_PHT   0xE40000   // bf16 ph_w^T
#define OFF_THT   0xE60000   // bf16 th_w^T
#define OFF_UB    0xE80000   // bf16 U = ow*g_w
#define OFF_VB    0xEA0000   // bf16 V = ph_w^T*th_w
#define OFF_UT    0xEC0000   // bf16 U^T
#define OFF_RPART 0xEE0000   // f32 [16][1024] row-sum partials
#define OFF_R     0xEF0000   // f32 [4][256]  r = bsf.1
#define OFF_UV    0xEF1000   // f32 [256]  u = ow*g_b
#define OFF_V2P   0xEF1400   // f32 [4][256]  v2 partials (v2 = ph_w^T*th_b)
#define OFF_W2P   0xEF2400   // f32 [4][256]  w2 partials (w2 = th_w^T*ph_b)
#define OFF_S2    0xEF3400   // f32 s2 = ph_b.th_b
#define OFF_CVEC  0xEF4000   // f32 [4][256]  U*r  (atomic-accumulated)
#define OFF_STATS 0xEF9000   // f32 [4][32][2] RAW (sum, sumsq) via atomics
#define OFF_W2SP  0xEFA000   // f32 [2][4][1024] w2sp partials (w2^T . bsf)
// ---------------------------------------------------------------------------

// ---------------- prep: weights/bias aux + 1024-block gather ----------------
// Round-10 lesson: the "direct fp32 U/V" branches were LDS-BROADCAST-bound
// (4096 wave-uniform ds_read_b32 per thread, ~5.8cyc each, x4 waves/CU =
// 40-55us straggler) - global-load unrolling couldn't fix it. Reverted to the
// measured-87.8us round-5 structure (MFMA U/V in p0 from transposed bf16
// weights). ONLY change vs that baseline: gather split 256 -> 1024 blocks
// (16ch x 64sp, mapping validated in R9/R10) for 4x latency hiding.
__global__ __launch_bounds__(256) void prep_k(
    const float* __restrict__ f0, const float* __restrict__ f1,
    const float* __restrict__ f2, const float* __restrict__ f3,
    const float* __restrict__ f4,
    const float* __restrict__ g_w, const float* __restrict__ ph_w,
    const float* __restrict__ th_w, const float* __restrict__ ow_w,
    const float* __restrict__ g_b, const float* __restrict__ ph_b,
    const float* __restrict__ th_b,
    char* __restrict__ ws)
{
  const int blk = blockIdx.x, t = threadIdx.x;
  __shared__ __attribute__((aligned(16))) union {
    __bf16 Lt[16][66];
    __bf16 T[64][72];
    float vec2[544];
  } sm;

  if (blk < 48) {
    // ---- weight transposes (fp32 -> bf16): gwT/phT/thT, 64x64 tiles
    const int w = blk >> 4, tl = blk & 15;
    const float* src = (w == 0) ? g_w : (w == 1) ? ph_w : th_w;
    __bf16* dst = (__bf16*)(ws + ((w == 0) ? OFF_GWT : (w == 1) ? OFF_PHT : OFF_THT));
    const int ti = (tl >> 2) * 64, tj = (tl & 3) * 64;
#pragma unroll
    for (int i = 0; i < 4; ++i) {
      int idx = i * 256 + t;
      int r = idx >> 4, c4 = (idx & 15) << 2;
      float4 v = *(const float4*)&src[(size_t)(ti + r) * 256 + tj + c4];
      sm.T[c4 + 0][r] = (__bf16)v.x;
      sm.T[c4 + 1][r] = (__bf16)v.y;
      sm.T[c4 + 2][r] = (__bf16)v.z;
      sm.T[c4 + 3][r] = (__bf16)v.w;
    }
    __syncthreads();
#pragma unroll
    for (int i = 0; i < 2; ++i) {
      int idx = i * 256 + t;
      int aa = idx >> 3, cc = (idx & 7) << 3;
      bf16x8 o = *(const bf16x8*)&sm.T[aa][cc];
      *(bf16x8*)&dst[(size_t)(tj + aa) * 256 + ti + cc] = o;
    }
  } else if (blk < 52) {
    // ---- owB plain convert
    const int r0 = (blk - 48) * 64;
    __bf16* owB = (__bf16*)(ws + OFF_OWB);
#pragma unroll
    for (int i = 0; i < 8; ++i) {
      int lin = i * 2048 + t * 8;
      size_t gidx = (size_t)r0 * 256 + lin;
      float4 v0 = *(const float4*)&ow_w[gidx];
      float4 v1 = *(const float4*)&ow_w[gidx + 4];
      bf16x8 o;
      o[0] = (__bf16)v0.x; o[1] = (__bf16)v0.y; o[2] = (__bf16)v0.z; o[3] = (__bf16)v0.w;
      o[4] = (__bf16)v1.x; o[5] = (__bf16)v1.y; o[6] = (__bf16)v1.z; o[7] = (__bf16)v1.w;
      *(bf16x8*)&owB[gidx] = o;
    }
  } else if (blk < 68) {
    // ---- uv = ow_w . g_b : 16 blocks x 16 rows, LDS tile reduction
    const int q = blk - 52;
    const int r0 = q * 16;
    float* uv = (float*)(ws + OFF_UV);
    sm.vec2[t] = g_b[t];
    __syncthreads();
    const int rl = t >> 4;             // 0..15 local row
    const int ci = (t & 15) * 16;      // column chunk start
    const float* p = ow_w + (size_t)(r0 + rl) * 256 + ci;
    float acc = 0.f;
#pragma unroll
    for (int u = 0; u < 4; ++u) {
      float4 v = *(const float4*)(p + u * 4);
      acc += v.x * sm.vec2[ci + u * 4]     + v.y * sm.vec2[ci + u * 4 + 1]
           + v.z * sm.vec2[ci + u * 4 + 2] + v.w * sm.vec2[ci + u * 4 + 3];
    }
    __syncthreads();
    sm.vec2[256 + rl * 17 + (t & 15)] = acc;
    __syncthreads();
    if (t < 16) {
      float s = 0.f;
#pragma unroll
      for (int i = 0; i < 16; ++i) s += sm.vec2[256 + t * 17 + i];
      uv[r0 + t] = s;
    }
  } else if (blk < 72) {
    // ---- v2 partials: v2part[q][t] = sum_{c in chunk q} ph_w[c][t]*th_b[c]
    const int q = blk - 68, c0 = q * 64;
    float* v2p = (float*)(ws + OFF_V2P);
    if (t < 64) sm.vec2[t] = th_b[c0 + t];
    __syncthreads();
    float acc = 0.f;
#pragma unroll 8
    for (int c = 0; c < 64; ++c)
      acc += ph_w[(size_t)(c0 + c) * 256 + t] * sm.vec2[c];
    v2p[q * 256 + t] = acc;
  } else if (blk < 76) {
    // ---- w2 partials: w2part[q][t] = sum_{c in chunk q} th_w[c][t]*ph_b[c]
    const int q = blk - 72, c0 = q * 64;
    float* w2p = (float*)(ws + OFF_W2P);
    if (t < 64) sm.vec2[t] = ph_b[c0 + t];
    __syncthreads();
    float acc = 0.f;
#pragma unroll 8
    for (int c = 0; c < 64; ++c)
      acc += th_w[(size_t)(c0 + c) * 256 + t] * sm.vec2[c];
    w2p[q * 256 + t] = acc;
  } else if (blk == 76) {
    // ---- s2 = ph_b.th_b ; zero raw GN stats
    float* s2 = (float*)(ws + OFF_S2);
    if (t < 64) {
      float pa = ph_b[t] * th_b[t] + ph_b[64 + t] * th_b[64 + t]
               + ph_b[128 + t] * th_b[128 + t] + ph_b[192 + t] * th_b[192 + t];
#pragma unroll
      for (int off = 32; off; off >>= 1) pa += __shfl_down(pa, off);
      if (t == 0) s2[0] = pa;
    }
    ((float*)(ws + OFF_STATS))[t] = 0.f;
  } else if (blk == 77) {
    // ---- zero cvec accumulator
    float* cvec = (float*)(ws + OFF_CVEC);
#pragma unroll
    for (int i = 0; i < 4; ++i) cvec[i * 256 + t] = 0.f;
  } else {
    // ---- gather: 16 channels x 64 spatial per block (1024 blocks)
    const int g = blk - 78;
    float*  bsf   = (float*)(ws + OFF_BSF);
    __bf16* bsfT  = (__bf16*)(ws + OFF_BSFT);
    __bf16* bsfB  = (__bf16*)(ws + OFF_BSFB);
    float*  rpart = (float*)(ws + OFF_RPART);
    const int sblk = g & 15, cgrp = (g >> 4) & 15, b = g >> 8;
    const int c0 = cgrp * 16, s0 = sblk * 64;
    const int spl = t & 63, sp = s0 + spl;
    const int y = sp >> 5, x = sp & 31;
#pragma unroll
    for (int i = 0; i < 4; ++i) {
      const int cl = (t >> 6) + i * 4;           // 0..15
      const int nc = b * 256 + c0 + cl;

      const float* p0 = f0 + (size_t)nc * 16384 + (y * 4) * 128 + x * 4;
      float4 r0 = *(const float4*)(p0);
      float4 r1 = *(const float4*)(p0 + 128);
      float4 r2 = *(const float4*)(p0 + 256);
      float4 r3 = *(const float4*)(p0 + 384);
      float a  = fmaxf(fmaxf(r0.x, r0.y), fmaxf(r0.z, r0.w));
      float bb = fmaxf(fmaxf(r1.x, r1.y), fmaxf(r1.z, r1.w));
      float c  = fmaxf(fmaxf(r2.x, r2.y), fmaxf(r2.z, r2.w));
      float d  = fmaxf(fmaxf(r3.x, r3.y), fmaxf(r3.z, r3.w));
      float m0v = fmaxf(fmaxf(a, bb), fmaxf(c, d));

      const float* p1 = f1 + (size_t)nc * 4096 + (y * 2) * 64 + x * 2;
      float2 s0v = *(const float2*)(p1);
      float2 s1v = *(const float2*)(p1 + 64);
      float m1v = fmaxf(fmaxf(s0v.x, s0v.y), fmaxf(s1v.x, s1v.y));

      float v2 = f2[(size_t)nc * 1024 + sp];
      float v3 = f3[(size_t)nc * 256 + (y >> 1) * 16 + (x >> 1)];
      float v4 = f4[(size_t)nc * 64  + (y >> 2) * 8  + (x >> 2)];
      float val = (m0v + m1v + v2 + v3 + v4) * 0.2f;
      bsf[(size_t)nc * 1024 + sp]  = val;
      bsfB[(size_t)nc * 1024 + sp] = (__bf16)val;
      sm.Lt[cl][spl] = (__bf16)val;
      float rs = val;
#pragma unroll
      for (int off = 32; off; off >>= 1) rs += __shfl_down(rs, off);
      if (spl == 0) rpart[sblk * 1024 + nc] = rs;
    }
    __syncthreads();
#pragma unroll
    for (int i = 0; i < 4; ++i) {
      int linear = t + i * 256;                  // 0..1023
      int spl2 = linear >> 4, cl2 = linear & 15;
      bsfT[((size_t)b * 1024 + s0 + spl2) * 256 + c0 + cl2] = sm.Lt[cl2][spl2];
    }
  }
}

// ---------------- GEMM accumulate core (64x64 tile, 4 waves, dbuf) ----------
__device__ __forceinline__ void gemm_acc(
    const __bf16* __restrict__ A, const __bf16* __restrict__ B,
    const int K, const int m0, const int n0,
    __bf16 (*Al)[64][72], __bf16 (*Bl)[64][72],
    f32x4 acc[2][2])
{
  const int t = threadIdx.x;
  const int lane = t & 63, wv = t >> 6;
  const int wm = (wv & 1) * 32, wn = (wv >> 1) * 32;
  const int fr = lane & 15, lk = (lane >> 4) * 8;
  const int sr = t >> 2, sk = (t & 3) * 16;

  const __bf16* Ar = A + (size_t)(m0 + sr) * K + sk;
  const __bf16* Br = B + (size_t)(n0 + sr) * K + sk;

  bf16x8 ra0 = *(const bf16x8*)(Ar);
  bf16x8 ra1 = *(const bf16x8*)(Ar + 8);
  bf16x8 rb0 = *(const bf16x8*)(Br);
  bf16x8 rb1 = *(const bf16x8*)(Br + 8);

  const int nIter = K >> 6;
  int p = 0;
  for (int it = 0; it < nIter; ++it) {
    *(bf16x8*)&Al[p][sr][sk]     = ra0;
    *(bf16x8*)&Al[p][sr][sk + 8] = ra1;
    *(bf16x8*)&Bl[p][sr][sk]     = rb0;
    *(bf16x8*)&Bl[p][sr][sk + 8] = rb1;
    __syncthreads();
    if (it + 1 < nIter) {
      const __bf16* An = Ar + (size_t)(it + 1) * 64;
      const __bf16* Bn = Br + (size_t)(it + 1) * 64;
      ra0 = *(const bf16x8*)(An);
      ra1 = *(const bf16x8*)(An + 8);
      rb0 = *(const bf16x8*)(Bn);
      rb1 = *(const bf16x8*)(Bn + 8);
    }
#pragma unroll
    for (int kk = 0; kk < 64; kk += 32) {
      bf16x8 a0 = *(const bf16x8*)&Al[p][wm + fr][kk + lk];
      bf16x8 a1 = *(const bf16x8*)&Al[p][wm + 16 + fr][kk + lk];
      bf16x8 b0 = *(const bf16x8*)&Bl[p][wn + fr][kk + lk];
      bf16x8 b1 = *(const bf16x8*)&Bl[p][wn + 16 + fr][kk + lk];
      acc[0][0] = __builtin_amdgcn_mfma_f32_16x16x32_bf16(a0, b0, acc[0][0], 0, 0, 0);
      acc[0][1] = __builtin_amdgcn_mfma_f32_16x16x32_bf16(a0, b1, acc[0][1], 0, 0, 0);
      acc[1][0] = __builtin_amdgcn_mfma_f32_16x16x32_bf16(a1, b0, acc[1][0], 0, 0, 0);
      acc[1][1] = __builtin_amdgcn_mfma_f32_16x16x32_bf16(a1, b1, acc[1][1], 0, 0, 0);
    }
    __syncthreads();
    p ^= 1;
  }
}

__device__ __forceinline__ void store_bf16(
    __bf16* dst, int ldst, const f32x4 acc[2][2],
    int m0, int n0, int wm, int wn, int rbase, int fr)
{
#pragma unroll
  for (int i = 0; i < 2; ++i)
#pragma unroll
    for (int r = 0; r < 4; ++r) {
      int m = m0 + wm + i * 16 + rbase + r;
#pragma unroll
      for (int j = 0; j < 2; ++j) {
        int n = n0 + wn + j * 16 + fr;
        dst[(size_t)m * ldst + n] = (__bf16)acc[i][j][r];
      }
    }
}

#define ZERO_ACC(acc) \
  _Pragma("unroll") for (int i_ = 0; i_ < 2; ++i_) \
  _Pragma("unroll") for (int j_ = 0; j_ < 2; ++j_) \
    acc[i_][j_] = (f32x4){0.f, 0.f, 0.f, 0.f};

// ---------------- P0: S hi/lo ; U(+UT) ; V ; r finalize ; w2sp parts --------
__global__ __launch_bounds__(256) void p0_k(char* __restrict__ ws)
{
  const int blk = blockIdx.x, t = threadIdx.x;
  __shared__ __attribute__((aligned(16))) __bf16 Al[2][64][72];
  __shared__ __attribute__((aligned(16))) __bf16 Bl[2][64][72];
  float* shf = (float*)(&Al[0][0][0]);

  const int lane = t & 63, wv = t >> 6;
  const int wm = (wv & 1) * 32, wn = (wv >> 1) * 32;
  const int fr = lane & 15, rbase = (lane >> 4) * 4;
  (void)lane; (void)wv;

  const __bf16* bsfB = (const __bf16*)(ws + OFF_BSFB);

  if (blk < 64) {
    // S = bsfB . bsfB^T (hi/lo bf16)
    const int b = blk >> 4, tl = blk & 15;
    const int m0 = (tl >> 2) * 64, n0 = (tl & 3) * 64;
    f32x4 acc[2][2]; ZERO_ACC(acc);
    gemm_acc(bsfB + (size_t)b * 262144, bsfB + (size_t)b * 262144,
             1024, m0, n0, Al, Bl, acc);
    __bf16* oh = (__bf16*)(ws + OFF_SBH) + (size_t)b * 65536;
    __bf16* ol = (__bf16*)(ws + OFF_SBL) + (size_t)b * 65536;
#pragma unroll
    for (int i = 0; i < 2; ++i)
#pragma unroll
      for (int r = 0; r < 4; ++r) {
        int m = m0 + wm + i * 16 + rbase + r;
#pragma unroll
        for (int j = 0; j < 2; ++j) {
          int n = n0 + wn + j * 16 + fr;
          float v = acc[i][j][r];
          __bf16 h = (__bf16)v;
          oh[(size_t)m * 256 + n] = h;
          ol[(size_t)m * 256 + n] = (__bf16)(v - (float)h);
        }
      }
  } else if (blk < 80) {
    // U = ow . g_w  (store U and U^T)
    const int tl = blk - 64;
    const int m0 = (tl >> 2) * 64, n0 = (tl & 3) * 64;
    f32x4 acc[2][2]; ZERO_ACC(acc);
    gemm_acc((const __bf16*)(ws + OFF_OWB), (const __bf16*)(ws + OFF_GWT),
             256, m0, n0, Al, Bl, acc);
    __bf16* ub = (__bf16*)(ws + OFF_UB);
    __bf16* ut = (__bf16*)(ws + OFF_UT);
#pragma unroll
    for (int i = 0; i < 2; ++i)
#pragma unroll
      for (int r = 0; r < 4; ++r) {
        int m = m0 + wm + i * 16 + rbase + r;
#pragma unroll
        for (int j = 0; j < 2; ++j) {
          int n = n0 + wn + j * 16 + fr;
          __bf16 v = (__bf16)acc[i][j][r];
          ub[(size_t)m * 256 + n] = v;
          ut[(size_t)n * 256 + m] = v;
        }
      }
  } else if (blk < 96) {
    // V = ph_w^T . th_w
    const int tl = blk - 80;
    const int m0 = (tl >> 2) * 64, n0 = (tl & 3) * 64;
    f32x4 acc[2][2]; ZERO_ACC(acc);
    gemm_acc((const __bf16*)(ws + OFF_PHT), (const __bf16*)(ws + OFF_THT),
             256, m0, n0, Al, Bl, acc);
    store_bf16((__bf16*)(ws + OFF_VB), 256, acc, m0, n0, wm, wn, rbase, fr);
  } else if (blk == 96) {
    // r finalize
    const float* rpart = (const float*)(ws + OFF_RPART);
    float* Rr = (float*)(ws + OFF_R);
#pragma unroll
    for (int j2 = 0; j2 < 4; ++j2) {
      int idx = t + j2 * 256;
      float s = 0.f;
#pragma unroll
      for (int k = 0; k < 16; ++k) s += rpart[k * 1024 + idx];
      Rr[idx] = s;
    }
  } else {
    // w2sp partials: w2spP[half][b][j] = sum_{c in half} w2[c]*bsf[b][c][j]
    const int q = blk - 97;              // 0..31
    const int half = q >> 4, idx = q & 15;
    const int b = idx >> 2, seg = (idx & 3) * 256;
    const int ch0 = half * 128;
    const float* w2p = (const float*)(ws + OFF_W2P);
    const float* bsf = (const float*)(ws + OFF_BSF);
    float* w2sp = (float*)(ws + OFF_W2SP);
    if (t < 128) {
      int c = ch0 + t;
      shf[t] = w2p[c] + w2p[256 + c] + w2p[512 + c] + w2p[768 + c];
    }
    __syncthreads();
    float acc = 0.f;
#pragma unroll 8
    for (int c = 0; c < 128; ++c)
      acc += shf[c] * bsf[((size_t)(b * 256 + ch0 + c)) * 1024 + seg + t];
    w2sp[half * 4096 + b * 1024 + seg + t] = acc;
  }
}

// ---------------- P1: T0' ; Yt(+v2 fold) ; cvec (chunked atomics) -----------
__global__ __launch_bounds__(256) void p1_k(char* __restrict__ ws)
{
  const int blk = blockIdx.x, t = threadIdx.x;
  __shared__ __attribute__((aligned(16))) __bf16 Al[2][64][72];
  __shared__ __attribute__((aligned(16))) __bf16 Bl[2][64][72];
  float* shf = (float*)(&Al[0][0][0]);

  const int lane = t & 63, wv = t >> 6;
  const int wm = (wv & 1) * 32, wn = (wv >> 1) * 32;
  const int fr = lane & 15, rbase = (lane >> 4) * 4;
  (void)lane; (void)wv;

  const __bf16* UB = (const __bf16*)(ws + OFF_UB);
  const float* Rr  = (const float*)(ws + OFF_R);
  const float* uv  = (const float*)(ws + OFF_UV);

  if (blk < 64) {
    // T0' = U*(Shi+Slo) + uv . r^T
    const int b = blk >> 4, tl = blk & 15;
    const int m0 = (tl >> 2) * 64, n0 = (tl & 3) * 64;
    f32x4 acc[2][2]; ZERO_ACC(acc);
    gemm_acc(UB, (const __bf16*)(ws + OFF_SBH) + (size_t)b * 65536,
             256, m0, n0, Al, Bl, acc);
    gemm_acc(UB, (const __bf16*)(ws + OFF_SBL) + (size_t)b * 65536,
             256, m0, n0, Al, Bl, acc);
    shf[t] = Rr[b * 256 + t];
    __syncthreads();
    __bf16* od = (__bf16*)(ws + OFF_T0) + (size_t)b * 65536;
#pragma unroll
    for (int i = 0; i < 2; ++i)
#pragma unroll
      for (int r = 0; r < 4; ++r) {
        int m = m0 + wm + i * 16 + rbase + r;
        float uvm = uv[m];
#pragma unroll
        for (int j = 0; j < 2; ++j) {
          int n = n0 + wn + j * 16 + fr;
          od[(size_t)m * 256 + n] = (__bf16)(acc[i][j][r] + uvm * shf[n]);
        }
      }
  } else if (blk < 320) {
    // Yt'[j][c] = sum_c' bsfT[j][c'] * V[c][c']  + v2[c]   (v2 fold)
    const int q = blk - 64;
    const int b = q >> 6, tl = q & 63;
    const int m0 = (tl >> 2) * 64, n0 = (tl & 3) * 64;   // m: spatial, n: chan
    f32x4 acc[2][2]; ZERO_ACC(acc);
    gemm_acc((const __bf16*)(ws + OFF_BSFT) + (size_t)b * 262144,
             (const __bf16*)(ws + OFF_VB), 256, m0, n0, Al, Bl, acc);
    const float* v2p = (const float*)(ws + OFF_V2P);
    shf[t] = v2p[t] + v2p[256 + t] + v2p[512 + t] + v2p[768 + t];
    __syncthreads();
    __bf16* od = (__bf16*)(ws + OFF_YT) + (size_t)b * 262144;
#pragma unroll
    for (int i = 0; i < 2; ++i)
#pragma unroll
      for (int r = 0; r < 4; ++r) {
        int m = m0 + wm + i * 16 + rbase + r;
#pragma unroll
        for (int j = 0; j < 2; ++j) {
          int n = n0 + wn + j * 16 + fr;
          od[(size_t)m * 256 + n] = (__bf16)(acc[i][j][r] + shf[n]);
        }
      }
  } else {
    // cvec[b] += UT-chunk^T . Rr[b]-chunk  (coalesced + f32 atomics)
    const int q = blk - 320;             // 0..15
    const int b = q >> 2, cc = (q & 3) * 64;
    const __bf16* UT = (const __bf16*)(ws + OFF_UT);
    float* cvec = (float*)(ws + OFF_CVEC);
    if (t < 64) shf[t] = Rr[b * 256 + cc + t];
    __syncthreads();
    float acc = 0.f;
#pragma unroll 8
    for (int c = 0; c < 64; ++c)
      acc += (float)UT[(size_t)(cc + c) * 256 + t] * shf[c];
    atomicAdd(&cvec[b * 256 + t], acc);
  }
}

// ---------------- P2: z = T0'*Yt'^T/N + coef*w2sp + s2*coef + ow_b ----------
__global__ __launch_bounds__(256) void p2_k(char* __restrict__ ws,
                                            const float* __restrict__ ow_b)
{
  const int blk = blockIdx.x, t = threadIdx.x;
  __shared__ __attribute__((aligned(16))) __bf16 Al[2][64][72];
  __shared__ __attribute__((aligned(16))) __bf16 Bl[2][64][72];
  float* shf = (float*)(&Al[0][0][0]);

  const int lane = t & 63, wv = t >> 6;
  const int wm = (wv & 1) * 32, wn = (wv >> 1) * 32;
  const int fr = lane & 15, rbase = (lane >> 4) * 4;

  const int b = blk >> 6, t6 = blk & 63;
  const int mt = t6 >> 4, nt = t6 & 15;
  const int m0 = mt * 64, n0 = nt * 64;
  (void)nt;

  f32x4 acc[2][2]; ZERO_ACC(acc);
  gemm_acc((const __bf16*)(ws + OFF_T0) + (size_t)b * 65536,
           (const __bf16*)(ws + OFF_YT) + (size_t)b * 262144,
           256, m0, n0, Al, Bl, acc);

  const float* uv   = (const float*)(ws + OFF_UV);
  const float* cvec = (const float*)(ws + OFF_CVEC);
  const float* w2sp = (const float*)(ws + OFF_W2SP);
  const float s2v   = *(const float*)(ws + OFF_S2);
  float* SRAW = (float*)(ws + OFF_STATS);
  float* zb = (float*)(ws + OFF_Z) + (size_t)b * 262144;

  float gs[2] = {0.f, 0.f}, gq[2] = {0.f, 0.f};
  int gidx[2];
  const float s1024 = 1.f / 1024.f;
#pragma unroll
  for (int i = 0; i < 2; ++i) {
    gidx[i] = (wm + i * 16 + rbase) >> 3;
#pragma unroll
    for (int r = 0; r < 4; ++r) {
      int m = m0 + wm + i * 16 + rbase + r;
      float coefm = uv[m] + cvec[b * 256 + m] * s1024;
      float qm = s2v * coefm + ow_b[m];
#pragma unroll
      for (int j = 0; j < 2; ++j) {
        int n = n0 + wn + j * 16 + fr;
        float w2n = w2sp[b * 1024 + n] + w2sp[4096 + b * 1024 + n];
        float v = acc[i][j][r] * s1024 + coefm * w2n + qm;
        zb[(size_t)m * 1024 + n] = v;
        gs[i] += v;
        gq[i] += v * v;
      }
    }
  }
  __syncthreads();
  if (t < 16) shf[t] = 0.f;
  __syncthreads();
#pragma unroll
  for (int i = 0; i < 2; ++i) {
    atomicAdd(&shf[gidx[i] * 2], gs[i]);
    atomicAdd(&shf[gidx[i] * 2 + 1], gq[i]);
  }
  __syncthreads();
  if (t < 16) {
    int g = mt * 8 + (t >> 1);
    atomicAdd(&SRAW[(b * 32 + g) * 2 + (t & 1)], shf[t]);
  }
}

// ---------------- fused GN + residual scatter (float4) ----------------------
__device__ __forceinline__ float4 gmix(float4 bz, float4 zz, float a, float c)
{
  float4 r;
  r.x = bz.x + zz.x * a + c;
  r.y = bz.y + zz.y * a + c;
  r.z = bz.z + zz.z * a + c;
  r.w = bz.w + zz.w * a + c;
  return r;
}
__device__ __forceinline__ float max4(float4 v)
{ return fmaxf(fmaxf(v.x, v.y), fmaxf(v.z, v.w)); }

// raw (sum, sumsq) -> (a = inv*gamma, c0 = beta - mean*a)
__device__ __forceinline__ void gn_coeff(const float2* __restrict__ ST,
                                         const float* __restrict__ gamma,
                                         const float* __restrict__ beta,
                                         int b, int ch, float& a, float& c0)
{
  float2 sq = ST[b * 32 + (ch >> 3)];
  float mean = sq.x * (1.0f / 8192.0f);
  float var  = sq.y * (1.0f / 8192.0f) - mean * mean;
  float inv  = rsqrtf(var + 1e-5f);
  a  = inv * gamma[ch];
  c0 = beta[ch] - mean * a;
}

__global__ __launch_bounds__(256) void scat_k(
    const char* __restrict__ ws,
    const float* __restrict__ f0, const float* __restrict__ f1,
    const float* __restrict__ f2, const float* __restrict__ f3,
    const float* __restrict__ f4,
    const float* __restrict__ gamma, const float* __restrict__ beta,
    float* __restrict__ out)
{
  const float* Z = (const float*)(ws + OFF_Z);
  const float* BSF = (const float*)(ws + OFF_BSF);
  const float2* ST = (const float2*)(ws + OFF_STATS);
  const int i4 = blockIdx.x * 256 + threadIdx.x;

  if (i4 < 4194304) {                       // f0: 128x128, upsample x4
    const int l = i4 << 2;
    const int x = l & 127, yy = (l >> 7) & 127, nc = l >> 14;
    const int ch = nc & 255, b = nc >> 8;
    float a, c0; gn_coeff(ST, gamma, beta, b, ch, a, c0);
    size_t base = (size_t)nc * 1024 + ((yy >> 2) << 5) + (x >> 2);
    float v = BSF[base] + Z[base] * a + c0;
    float4 f = ((const float4*)f0)[i4];
    float4 o; o.x = f.x + v; o.y = f.y + v; o.z = f.z + v; o.w = f.w + v;
    ((float4*)out)[i4] = o;
  } else if (i4 < 5242880) {                // f1: 64x64, upsample x2
    const int l4 = i4 - 4194304;
    const int l = l4 << 2;
    const int x = l & 63, yy = (l >> 6) & 63, nc = l >> 12;
    const int ch = nc & 255, b = nc >> 8;
    float a, c0; gn_coeff(ST, gamma, beta, b, ch, a, c0);
    size_t base = (size_t)nc * 1024 + ((yy >> 1) << 5) + (x >> 1);
    float v0 = BSF[base] + Z[base] * a + c0;
    float v1 = BSF[base + 1] + Z[base + 1] * a + c0;
    float4 f = ((const float4*)f1)[l4];
    float4 o; o.x = f.x + v0; o.y = f.y + v0; o.z = f.z + v1; o.w = f.w + v1;
    ((float4*)out)[i4] = o;
  } else if (i4 < 5505024) {                // f2: 32x32, identity
    const int l4 = i4 - 5242880;
    const int l = l4 << 2;
    const int nc = l >> 10, e = l & 1023;
    const int ch = nc & 255, b = nc >> 8;
    float a, c0; gn_coeff(ST, gamma, beta, b, ch, a, c0);
    size_t base = (size_t)nc * 1024 + e;
    float4 z4 = *(const float4*)&Z[base];
    float4 b4 = *(const float4*)&BSF[base];
    float4 v = gmix(b4, z4, a, c0);
    float4 f = ((const float4*)f2)[l4];
    float4 o; o.x = f.x + v.x; o.y = f.y + v.y; o.z = f.z + v.z; o.w = f.w + v.w;
    ((float4*)out)[i4] = o;
  } else if (i4 < 5570560) {                // f3: 16x16, maxpool 2x2
    const int l4 = i4 - 5505024;
    const int l = l4 << 2;
    const int x = l & 15, yy = (l >> 4) & 15, nc = l >> 8;
    const int ch = nc & 255, b = nc >> 8;
    float a, c0; gn_coeff(ST, gamma, beta, b, ch, a, c0);
    size_t base = (size_t)nc * 1024;
    const int p0 = (yy * 2) * 32 + (x * 2);
    float4 r0a = gmix(*(const float4*)&BSF[base + p0],      *(const float4*)&Z[base + p0],      a, c0);
    float4 r0b = gmix(*(const float4*)&BSF[base + p0 + 4],  *(const float4*)&Z[base + p0 + 4],  a, c0);
    float4 r1a = gmix(*(const float4*)&BSF[base + p0 + 32], *(const float4*)&Z[base + p0 + 32], a, c0);
    float4 r1b = gmix(*(const float4*)&BSF[base + p0 + 36], *(const float4*)&Z[base + p0 + 36], a, c0);
    float4 f = ((const float4*)f3)[l4];
    float4 o;
    o.x = f.x + fmaxf(fmaxf(r0a.x, r0a.y), fmaxf(r1a.x, r1a.y));
    o.y = f.y + fmaxf(fmaxf(r0a.z, r0a.w), fmaxf(r1a.z, r1a.w));
    o.z = f.z + fmaxf(fmaxf(r0b.x, r0b.y), fmaxf(r1b.x, r1b.y));
    o.w = f.w + fmaxf(fmaxf(r0b.z, r0b.w), fmaxf(r1b.z, r1b.w));
    ((float4*)out)[i4] = o;
  } else {                                   // f4: 8x8, maxpool 4x4
    const int l4 = i4 - 5570560;
    const int l = l4 << 2;
    const int x = l & 7, yy = (l >> 3) & 7, nc = l >> 6;
    const int ch = nc & 255, b = nc >> 8;
    float a, c0; gn_coeff(ST, gamma, beta, b, ch, a, c0);
    size_t base = (size_t)nc * 1024;
    float4 mx = {-3.4e38f, -3.4e38f, -3.4e38f, -3.4e38f};
#pragma unroll
    for (int r = 0; r < 4; ++r) {
      const float* zp = &Z[base + (size_t)(yy * 4 + r) * 32 + x * 4];
      const float* bp = &BSF[base + (size_t)(yy * 4 + r) * 32 + x * 4];
      float4 q0 = gmix(*(const float4*)(bp),      *(const float4*)(zp),      a, c0);
      float4 q1 = gmix(*(const float4*)(bp + 4),  *(const float4*)(zp + 4),  a, c0);
      float4 q2 = gmix(*(const float4*)(bp + 8),  *(const float4*)(zp + 8),  a, c0);
      float4 q3 = gmix(*(const float4*)(bp + 12), *(const float4*)(zp + 12), a, c0);
      mx.x = fmaxf(mx.x, max4(q0));
      mx.y = fmaxf(mx.y, max4(q1));
      mx.z = fmaxf(mx.z, max4(q2));
      mx.w = fmaxf(mx.w, max4(q3));
    }
    float4 f = ((const float4*)f4)[l4];
    float4 o; o.x = f.x + mx.x; o.y = f.y + mx.y; o.z = f.z + mx.z; o.w = f.w + mx.w;
    ((float4*)out)[i4] = o;
  }
}

// ---------------------------------------------------------------------------
extern "C" void kernel_launch(void* const* d_in, const int* in_sizes, int n_in,
                              void* d_out, int out_size, void* d_ws, size_t ws_size,
                              hipStream_t stream)
{
  (void)in_sizes; (void)n_in; (void)out_size; (void)ws_size;
  const float* f0   = (const float*)d_in[0];
  const float* f1   = (const float*)d_in[1];
  const float* f2   = (const float*)d_in[2];
  const float* f3   = (const float*)d_in[3];
  const float* f4   = (const float*)d_in[4];
  const float* g_w  = (const float*)d_in[5];
  const float* g_b  = (const float*)d_in[6];
  const float* th_w = (const float*)d_in[7];
  const float* th_b = (const float*)d_in[8];
  const float* ph_w = (const float*)d_in[9];
  const float* ph_b = (const float*)d_in[10];
  const float* ow_w = (const float*)d_in[11];
  const float* ow_b = (const float*)d_in[12];
  const float* gn_g = (const float*)d_in[13];
  const float* gn_b = (const float*)d_in[14];
  char* ws = (char*)d_ws;

  // 1) aux (blocks 0-77) + gather (blocks 78-1101, 4x latency hiding)
  prep_k<<<1102, 256, 0, stream>>>(f0, f1, f2, f3, f4,
                                   g_w, ph_w, th_w, ow_w,
                                   g_b, ph_b, th_b, ws);
  // 2) S (hi/lo) ; U+UT ; V ; r ; w2sp parts
  p0_k<<<129, 256, 0, stream>>>(ws);
  // 3) T0' ; Yt(+v2 fold) ; cvec
  p1_k<<<336, 256, 0, stream>>>(ws);
  // 4) z + GN raw stats
  p2_k<<<256, 256, 0, stream>>>(ws, ow_b);
  // 5) fused GN-normalize + residual scatter
  scat_k<<<21824, 256, 0, stream>>>(ws, f0, f1, f2, f3, f4, gn_g, gn_b,
                                    (float*)d_out);
}

// Round 12
// 76.251 us; speedup vs baseline: 1.3970x; 1.1195x over previous
//
#include <hip/hip_runtime.h>

typedef __bf16 bf16x8 __attribute__((ext_vector_type(8)));
typedef __bf16 bf16x4v __attribute__((ext_vector_type(4)));
typedef float f32x4 __attribute__((ext_vector_type(4)));

// ---------------------------------------------------------------------------
// Workspace layout (bytes):
//   (0x000000 free — f32 bsf copy eliminated in round 12)
#define OFF_BSFT  0x400000   // bf16 [4][1024][256]  2 MB   (spatial-major)
#define OFF_BSFB  0x600000   // bf16 [4][256][1024]  2 MB   (ch-major; the ONLY bsf copy)
#define OFF_ZB    0x800000   // bf16 [4][256][1024]  2 MB   z (quantized; stats from f32)
#define OFF_SBH   0xC00000   // bf16 [4][256][256]   512 KB  S hi
#define OFF_SBL   0xC80000   // bf16 [4][256][256]   512 KB  S lo (residual)
#define OFF_T0    0xD00000   // bf16 [4][256][256]   T0' = U*S + uv*r^T
#define OFF_OWB   0xE00000   // bf16 [256][256]
#define OFF_GWT   0xE20000   // bf16 g_w^T
#define OFF_PHT   0xE40000   // bf16 ph_w^T
#define OFF_THT   0xE60000   // bf16 th_w^T
#define OFF_UB    0xE80000   // bf16 U = ow*g_w
#define OFF_VB    0xEA0000   // bf16 V = ph_w^T*th_w
#define OFF_UT    0xEC0000   // bf16 U^T
#define OFF_RPART 0xEE0000   // f32 [16][1024] row-sum partials
#define OFF_R     0xEF0000   // f32 [4][256]  r = bsf.1
#define OFF_UV    0xEF1000   // f32 [256]  u = ow*g_b
#define OFF_V2P   0xEF1400   // f32 [4][256]  v2 partials (v2 = ph_w^T*th_b)
#define OFF_W2P   0xEF2400   // f32 [4][256]  w2 partials (w2 = th_w^T*ph_b)
#define OFF_S2    0xEF3400   // f32 s2 = ph_b.th_b
#define OFF_CVEC  0xEF4000   // f32 [4][256]  U*r  (atomic-accumulated)
#define OFF_STATS 0xEF9000   // f32 [4][32][2] RAW (sum, sumsq) via atomics
#define OFF_W2SP  0xEFA000   // f32 [2][4][1024] w2sp partials, ends 0xF02000
#define OFF_YT    0xF10000   // bf16 [4][1024][256]  2 MB  Yt (own region -> bsfB survives)
// ---------------------------------------------------------------------------

// ---------------- prep: weights/bias aux + 1024-block gather ----------------
__global__ __launch_bounds__(256) void prep_k(
    const float* __restrict__ f0, const float* __restrict__ f1,
    const float* __restrict__ f2, const float* __restrict__ f3,
    const float* __restrict__ f4,
    const float* __restrict__ g_w, const float* __restrict__ ph_w,
    const float* __restrict__ th_w, const float* __restrict__ ow_w,
    const float* __restrict__ g_b, const float* __restrict__ ph_b,
    const float* __restrict__ th_b,
    char* __restrict__ ws)
{
  const int blk = blockIdx.x, t = threadIdx.x;
  __shared__ __attribute__((aligned(16))) union {
    __bf16 Lt[16][66];
    __bf16 T[64][72];
    float vec2[544];
  } sm;

  if (blk < 48) {
    // ---- weight transposes (fp32 -> bf16): gwT/phT/thT, 64x64 tiles
    const int w = blk >> 4, tl = blk & 15;
    const float* src = (w == 0) ? g_w : (w == 1) ? ph_w : th_w;
    __bf16* dst = (__bf16*)(ws + ((w == 0) ? OFF_GWT : (w == 1) ? OFF_PHT : OFF_THT));
    const int ti = (tl >> 2) * 64, tj = (tl & 3) * 64;
#pragma unroll
    for (int i = 0; i < 4; ++i) {
      int idx = i * 256 + t;
      int r = idx >> 4, c4 = (idx & 15) << 2;
      float4 v = *(const float4*)&src[(size_t)(ti + r) * 256 + tj + c4];
      sm.T[c4 + 0][r] = (__bf16)v.x;
      sm.T[c4 + 1][r] = (__bf16)v.y;
      sm.T[c4 + 2][r] = (__bf16)v.z;
      sm.T[c4 + 3][r] = (__bf16)v.w;
    }
    __syncthreads();
#pragma unroll
    for (int i = 0; i < 2; ++i) {
      int idx = i * 256 + t;
      int aa = idx >> 3, cc = (idx & 7) << 3;
      bf16x8 o = *(const bf16x8*)&sm.T[aa][cc];
      *(bf16x8*)&dst[(size_t)(tj + aa) * 256 + ti + cc] = o;
    }
  } else if (blk < 52) {
    // ---- owB plain convert
    const int r0 = (blk - 48) * 64;
    __bf16* owB = (__bf16*)(ws + OFF_OWB);
#pragma unroll
    for (int i = 0; i < 8; ++i) {
      int lin = i * 2048 + t * 8;
      size_t gidx = (size_t)r0 * 256 + lin;
      float4 v0 = *(const float4*)&ow_w[gidx];
      float4 v1 = *(const float4*)&ow_w[gidx + 4];
      bf16x8 o;
      o[0] = (__bf16)v0.x; o[1] = (__bf16)v0.y; o[2] = (__bf16)v0.z; o[3] = (__bf16)v0.w;
      o[4] = (__bf16)v1.x; o[5] = (__bf16)v1.y; o[6] = (__bf16)v1.z; o[7] = (__bf16)v1.w;
      *(bf16x8*)&owB[gidx] = o;
    }
  } else if (blk < 68) {
    // ---- uv = ow_w . g_b : 16 blocks x 16 rows, LDS tile reduction
    const int q = blk - 52;
    const int r0 = q * 16;
    float* uv = (float*)(ws + OFF_UV);
    sm.vec2[t] = g_b[t];
    __syncthreads();
    const int rl = t >> 4;             // 0..15 local row
    const int ci = (t & 15) * 16;      // column chunk start
    const float* p = ow_w + (size_t)(r0 + rl) * 256 + ci;
    float acc = 0.f;
#pragma unroll
    for (int u = 0; u < 4; ++u) {
      float4 v = *(const float4*)(p + u * 4);
      acc += v.x * sm.vec2[ci + u * 4]     + v.y * sm.vec2[ci + u * 4 + 1]
           + v.z * sm.vec2[ci + u * 4 + 2] + v.w * sm.vec2[ci + u * 4 + 3];
    }
    __syncthreads();
    sm.vec2[256 + rl * 17 + (t & 15)] = acc;
    __syncthreads();
    if (t < 16) {
      float s = 0.f;
#pragma unroll
      for (int i = 0; i < 16; ++i) s += sm.vec2[256 + t * 17 + i];
      uv[r0 + t] = s;
    }
  } else if (blk < 72) {
    // ---- v2 partials: v2part[q][t] = sum_{c in chunk q} ph_w[c][t]*th_b[c]
    const int q = blk - 68, c0 = q * 64;
    float* v2p = (float*)(ws + OFF_V2P);
    if (t < 64) sm.vec2[t] = th_b[c0 + t];
    __syncthreads();
    float acc = 0.f;
#pragma unroll 8
    for (int c = 0; c < 64; ++c)
      acc += ph_w[(size_t)(c0 + c) * 256 + t] * sm.vec2[c];
    v2p[q * 256 + t] = acc;
  } else if (blk < 76) {
    // ---- w2 partials: w2part[q][t] = sum_{c in chunk q} th_w[c][t]*ph_b[c]
    const int q = blk - 72, c0 = q * 64;
    float* w2p = (float*)(ws + OFF_W2P);
    if (t < 64) sm.vec2[t] = ph_b[c0 + t];
    __syncthreads();
    float acc = 0.f;
#pragma unroll 8
    for (int c = 0; c < 64; ++c)
      acc += th_w[(size_t)(c0 + c) * 256 + t] * sm.vec2[c];
    w2p[q * 256 + t] = acc;
  } else if (blk == 76) {
    // ---- s2 = ph_b.th_b ; zero raw GN stats
    float* s2 = (float*)(ws + OFF_S2);
    if (t < 64) {
      float pa = ph_b[t] * th_b[t] + ph_b[64 + t] * th_b[64 + t]
               + ph_b[128 + t] * th_b[128 + t] + ph_b[192 + t] * th_b[192 + t];
#pragma unroll
      for (int off = 32; off; off >>= 1) pa += __shfl_down(pa, off);
      if (t == 0) s2[0] = pa;
    }
    ((float*)(ws + OFF_STATS))[t] = 0.f;
  } else if (blk == 77) {
    // ---- zero cvec accumulator
    float* cvec = (float*)(ws + OFF_CVEC);
#pragma unroll
    for (int i = 0; i < 4; ++i) cvec[i * 256 + t] = 0.f;
  } else {
    // ---- gather: 16 channels x 64 spatial per block (1024 blocks)
    // Round-12: f32 bsf store removed; bsfB (bf16) is the only copy.
    const int g = blk - 78;
    __bf16* bsfT  = (__bf16*)(ws + OFF_BSFT);
    __bf16* bsfB  = (__bf16*)(ws + OFF_BSFB);
    float*  rpart = (float*)(ws + OFF_RPART);
    const int sblk = g & 15, cgrp = (g >> 4) & 15, b = g >> 8;
    const int c0 = cgrp * 16, s0 = sblk * 64;
    const int spl = t & 63, sp = s0 + spl;
    const int y = sp >> 5, x = sp & 31;
#pragma unroll
    for (int i = 0; i < 4; ++i) {
      const int cl = (t >> 6) + i * 4;           // 0..15
      const int nc = b * 256 + c0 + cl;

      const float* p0 = f0 + (size_t)nc * 16384 + (y * 4) * 128 + x * 4;
      float4 r0 = *(const float4*)(p0);
      float4 r1 = *(const float4*)(p0 + 128);
      float4 r2 = *(const float4*)(p0 + 256);
      float4 r3 = *(const float4*)(p0 + 384);
      float a  = fmaxf(fmaxf(r0.x, r0.y), fmaxf(r0.z, r0.w));
      float bb = fmaxf(fmaxf(r1.x, r1.y), fmaxf(r1.z, r1.w));
      float c  = fmaxf(fmaxf(r2.x, r2.y), fmaxf(r2.z, r2.w));
      float d  = fmaxf(fmaxf(r3.x, r3.y), fmaxf(r3.z, r3.w));
      float m0v = fmaxf(fmaxf(a, bb), fmaxf(c, d));

      const float* p1 = f1 + (size_t)nc * 4096 + (y * 2) * 64 + x * 2;
      float2 s0v = *(const float2*)(p1);
      float2 s1v = *(const float2*)(p1 + 64);
      float m1v = fmaxf(fmaxf(s0v.x, s0v.y), fmaxf(s1v.x, s1v.y));

      float v2 = f2[(size_t)nc * 1024 + sp];
      float v3 = f3[(size_t)nc * 256 + (y >> 1) * 16 + (x >> 1)];
      float v4 = f4[(size_t)nc * 64  + (y >> 2) * 8  + (x >> 2)];
      float val = (m0v + m1v + v2 + v3 + v4) * 0.2f;
      bsfB[(size_t)nc * 1024 + sp] = (__bf16)val;
      sm.Lt[cl][spl] = (__bf16)val;
      float rs = val;
#pragma unroll
      for (int off = 32; off; off >>= 1) rs += __shfl_down(rs, off);
      if (spl == 0) rpart[sblk * 1024 + nc] = rs;
    }
    __syncthreads();
#pragma unroll
    for (int i = 0; i < 4; ++i) {
      int linear = t + i * 256;                  // 0..1023
      int spl2 = linear >> 4, cl2 = linear & 15;
      bsfT[((size_t)b * 1024 + s0 + spl2) * 256 + c0 + cl2] = sm.Lt[cl2][spl2];
    }
  }
}

// ---------------- GEMM accumulate core (64x64 tile, 4 waves, dbuf) ----------
__device__ __forceinline__ void gemm_acc(
    const __bf16* __restrict__ A, const __bf16* __restrict__ B,
    const int K, const int m0, const int n0,
    __bf16 (*Al)[64][72], __bf16 (*Bl)[64][72],
    f32x4 acc[2][2])
{
  const int t = threadIdx.x;
  const int lane = t & 63, wv = t >> 6;
  const int wm = (wv & 1) * 32, wn = (wv >> 1) * 32;
  const int fr = lane & 15, lk = (lane >> 4) * 8;
  const int sr = t >> 2, sk = (t & 3) * 16;

  const __bf16* Ar = A + (size_t)(m0 + sr) * K + sk;
  const __bf16* Br = B + (size_t)(n0 + sr) * K + sk;

  bf16x8 ra0 = *(const bf16x8*)(Ar);
  bf16x8 ra1 = *(const bf16x8*)(Ar + 8);
  bf16x8 rb0 = *(const bf16x8*)(Br);
  bf16x8 rb1 = *(const bf16x8*)(Br + 8);

  const int nIter = K >> 6;
  int p = 0;
  for (int it = 0; it < nIter; ++it) {
    *(bf16x8*)&Al[p][sr][sk]     = ra0;
    *(bf16x8*)&Al[p][sr][sk + 8] = ra1;
    *(bf16x8*)&Bl[p][sr][sk]     = rb0;
    *(bf16x8*)&Bl[p][sr][sk + 8] = rb1;
    __syncthreads();
    if (it + 1 < nIter) {
      const __bf16* An = Ar + (size_t)(it + 1) * 64;
      const __bf16* Bn = Br + (size_t)(it + 1) * 64;
      ra0 = *(const bf16x8*)(An);
      ra1 = *(const bf16x8*)(An + 8);
      rb0 = *(const bf16x8*)(Bn);
      rb1 = *(const bf16x8*)(Bn + 8);
    }
#pragma unroll
    for (int kk = 0; kk < 64; kk += 32) {
      bf16x8 a0 = *(const bf16x8*)&Al[p][wm + fr][kk + lk];
      bf16x8 a1 = *(const bf16x8*)&Al[p][wm + 16 + fr][kk + lk];
      bf16x8 b0 = *(const bf16x8*)&Bl[p][wn + fr][kk + lk];
      bf16x8 b1 = *(const bf16x8*)&Bl[p][wn + 16 + fr][kk + lk];
      acc[0][0] = __builtin_amdgcn_mfma_f32_16x16x32_bf16(a0, b0, acc[0][0], 0, 0, 0);
      acc[0][1] = __builtin_amdgcn_mfma_f32_16x16x32_bf16(a0, b1, acc[0][1], 0, 0, 0);
      acc[1][0] = __builtin_amdgcn_mfma_f32_16x16x32_bf16(a1, b0, acc[1][0], 0, 0, 0);
      acc[1][1] = __builtin_amdgcn_mfma_f32_16x16x32_bf16(a1, b1, acc[1][1], 0, 0, 0);
    }
    __syncthreads();
    p ^= 1;
  }
}

__device__ __forceinline__ void store_bf16(
    __bf16* dst, int ldst, const f32x4 acc[2][2],
    int m0, int n0, int wm, int wn, int rbase, int fr)
{
#pragma unroll
  for (int i = 0; i < 2; ++i)
#pragma unroll
    for (int r = 0; r < 4; ++r) {
      int m = m0 + wm + i * 16 + rbase + r;
#pragma unroll
      for (int j = 0; j < 2; ++j) {
        int n = n0 + wn + j * 16 + fr;
        dst[(size_t)m * ldst + n] = (__bf16)acc[i][j][r];
      }
    }
}

#define ZERO_ACC(acc) \
  _Pragma("unroll") for (int i_ = 0; i_ < 2; ++i_) \
  _Pragma("unroll") for (int j_ = 0; j_ < 2; ++j_) \
    acc[i_][j_] = (f32x4){0.f, 0.f, 0.f, 0.f};

// ---------------- P0: S hi/lo ; U(+UT) ; V ; r finalize ; w2sp parts --------
__global__ __launch_bounds__(256) void p0_k(char* __restrict__ ws)
{
  const int blk = blockIdx.x, t = threadIdx.x;
  __shared__ __attribute__((aligned(16))) __bf16 Al[2][64][72];
  __shared__ __attribute__((aligned(16))) __bf16 Bl[2][64][72];
  float* shf = (float*)(&Al[0][0][0]);

  const int lane = t & 63, wv = t >> 6;
  const int wm = (wv & 1) * 32, wn = (wv >> 1) * 32;
  const int fr = lane & 15, rbase = (lane >> 4) * 4;
  (void)lane; (void)wv;

  const __bf16* bsfB = (const __bf16*)(ws + OFF_BSFB);

  if (blk < 64) {
    // S = bsfB . bsfB^T (hi/lo bf16)
    const int b = blk >> 4, tl = blk & 15;
    const int m0 = (tl >> 2) * 64, n0 = (tl & 3) * 64;
    f32x4 acc[2][2]; ZERO_ACC(acc);
    gemm_acc(bsfB + (size_t)b * 262144, bsfB + (size_t)b * 262144,
             1024, m0, n0, Al, Bl, acc);
    __bf16* oh = (__bf16*)(ws + OFF_SBH) + (size_t)b * 65536;
    __bf16* ol = (__bf16*)(ws + OFF_SBL) + (size_t)b * 65536;
#pragma unroll
    for (int i = 0; i < 2; ++i)
#pragma unroll
      for (int r = 0; r < 4; ++r) {
        int m = m0 + wm + i * 16 + rbase + r;
#pragma unroll
        for (int j = 0; j < 2; ++j) {
          int n = n0 + wn + j * 16 + fr;
          float v = acc[i][j][r];
          __bf16 h = (__bf16)v;
          oh[(size_t)m * 256 + n] = h;
          ol[(size_t)m * 256 + n] = (__bf16)(v - (float)h);
        }
      }
  } else if (blk < 80) {
    // U = ow . g_w  (store U and U^T)
    const int tl = blk - 64;
    const int m0 = (tl >> 2) * 64, n0 = (tl & 3) * 64;
    f32x4 acc[2][2]; ZERO_ACC(acc);
    gemm_acc((const __bf16*)(ws + OFF_OWB), (const __bf16*)(ws + OFF_GWT),
             256, m0, n0, Al, Bl, acc);
    __bf16* ub = (__bf16*)(ws + OFF_UB);
    __bf16* ut = (__bf16*)(ws + OFF_UT);
#pragma unroll
    for (int i = 0; i < 2; ++i)
#pragma unroll
      for (int r = 0; r < 4; ++r) {
        int m = m0 + wm + i * 16 + rbase + r;
#pragma unroll
        for (int j = 0; j < 2; ++j) {
          int n = n0 + wn + j * 16 + fr;
          __bf16 v = (__bf16)acc[i][j][r];
          ub[(size_t)m * 256 + n] = v;
          ut[(size_t)n * 256 + m] = v;
        }
      }
  } else if (blk < 96) {
    // V = ph_w^T . th_w
    const int tl = blk - 80;
    const int m0 = (tl >> 2) * 64, n0 = (tl & 3) * 64;
    f32x4 acc[2][2]; ZERO_ACC(acc);
    gemm_acc((const __bf16*)(ws + OFF_PHT), (const __bf16*)(ws + OFF_THT),
             256, m0, n0, Al, Bl, acc);
    store_bf16((__bf16*)(ws + OFF_VB), 256, acc, m0, n0, wm, wn, rbase, fr);
  } else if (blk == 96) {
    // r finalize
    const float* rpart = (const float*)(ws + OFF_RPART);
    float* Rr = (float*)(ws + OFF_R);
#pragma unroll
    for (int j2 = 0; j2 < 4; ++j2) {
      int idx = t + j2 * 256;
      float s = 0.f;
#pragma unroll
      for (int k = 0; k < 16; ++k) s += rpart[k * 1024 + idx];
      Rr[idx] = s;
    }
  } else {
    // w2sp partials: w2spP[half][b][j] = sum_{c in half} w2[c]*bsfB[b][c][j]
    const int q = blk - 97;              // 0..31
    const int half = q >> 4, idx = q & 15;
    const int b = idx >> 2, seg = (idx & 3) * 256;
    const int ch0 = half * 128;
    const float* w2p = (const float*)(ws + OFF_W2P);
    float* w2sp = (float*)(ws + OFF_W2SP);
    if (t < 128) {
      int c = ch0 + t;
      shf[t] = w2p[c] + w2p[256 + c] + w2p[512 + c] + w2p[768 + c];
    }
    __syncthreads();
    float acc = 0.f;
#pragma unroll 8
    for (int c = 0; c < 128; ++c)
      acc += shf[c] * (float)bsfB[((size_t)(b * 256 + ch0 + c)) * 1024 + seg + t];
    w2sp[half * 4096 + b * 1024 + seg + t] = acc;
  }
}

// ---------------- P1: T0' ; Yt(+v2 fold) ; cvec (chunked atomics) -----------
__global__ __launch_bounds__(256) void p1_k(char* __restrict__ ws)
{
  const int blk = blockIdx.x, t = threadIdx.x;
  __shared__ __attribute__((aligned(16))) __bf16 Al[2][64][72];
  __shared__ __attribute__((aligned(16))) __bf16 Bl[2][64][72];
  float* shf = (float*)(&Al[0][0][0]);

  const int lane = t & 63, wv = t >> 6;
  const int wm = (wv & 1) * 32, wn = (wv >> 1) * 32;
  const int fr = lane & 15, rbase = (lane >> 4) * 4;
  (void)lane; (void)wv;

  const __bf16* UB = (const __bf16*)(ws + OFF_UB);
  const float* Rr  = (const float*)(ws + OFF_R);
  const float* uv  = (const float*)(ws + OFF_UV);

  if (blk < 64) {
    // T0' = U*(Shi+Slo) + uv . r^T
    const int b = blk >> 4, tl = blk & 15;
    const int m0 = (tl >> 2) * 64, n0 = (tl & 3) * 64;
    f32x4 acc[2][2]; ZERO_ACC(acc);
    gemm_acc(UB, (const __bf16*)(ws + OFF_SBH) + (size_t)b * 65536,
             256, m0, n0, Al, Bl, acc);
    gemm_acc(UB, (const __bf16*)(ws + OFF_SBL) + (size_t)b * 65536,
             256, m0, n0, Al, Bl, acc);
    shf[t] = Rr[b * 256 + t];
    __syncthreads();
    __bf16* od = (__bf16*)(ws + OFF_T0) + (size_t)b * 65536;
#pragma unroll
    for (int i = 0; i < 2; ++i)
#pragma unroll
      for (int r = 0; r < 4; ++r) {
        int m = m0 + wm + i * 16 + rbase + r;
        float uvm = uv[m];
#pragma unroll
        for (int j = 0; j < 2; ++j) {
          int n = n0 + wn + j * 16 + fr;
          od[(size_t)m * 256 + n] = (__bf16)(acc[i][j][r] + uvm * shf[n]);
        }
      }
  } else if (blk < 320) {
    // Yt'[j][c] = sum_c' bsfT[j][c'] * V[c][c']  + v2[c]   (v2 fold)
    const int q = blk - 64;
    const int b = q >> 6, tl = q & 63;
    const int m0 = (tl >> 2) * 64, n0 = (tl & 3) * 64;   // m: spatial, n: chan
    f32x4 acc[2][2]; ZERO_ACC(acc);
    gemm_acc((const __bf16*)(ws + OFF_BSFT) + (size_t)b * 262144,
             (const __bf16*)(ws + OFF_VB), 256, m0, n0, Al, Bl, acc);
    const float* v2p = (const float*)(ws + OFF_V2P);
    shf[t] = v2p[t] + v2p[256 + t] + v2p[512 + t] + v2p[768 + t];
    __syncthreads();
    __bf16* od = (__bf16*)(ws + OFF_YT) + (size_t)b * 262144;
#pragma unroll
    for (int i = 0; i < 2; ++i)
#pragma unroll
      for (int r = 0; r < 4; ++r) {
        int m = m0 + wm + i * 16 + rbase + r;
#pragma unroll
        for (int j = 0; j < 2; ++j) {
          int n = n0 + wn + j * 16 + fr;
          od[(size_t)m * 256 + n] = (__bf16)(acc[i][j][r] + shf[n]);
        }
      }
  } else {
    // cvec[b] += UT-chunk^T . Rr[b]-chunk  (coalesced + f32 atomics)
    const int q = blk - 320;             // 0..15
    const int b = q >> 2, cc = (q & 3) * 64;
    const __bf16* UT = (const __bf16*)(ws + OFF_UT);
    float* cvec = (float*)(ws + OFF_CVEC);
    if (t < 64) shf[t] = Rr[b * 256 + cc + t];
    __syncthreads();
    float acc = 0.f;
#pragma unroll 8
    for (int c = 0; c < 64; ++c)
      acc += (float)UT[(size_t)(cc + c) * 256 + t] * shf[c];
    atomicAdd(&cvec[b * 256 + t], acc);
  }
}

// ---------------- P2: z = T0'*Yt'^T/N + coef*w2sp + s2*coef + ow_b ----------
// z written as bf16 (ZB); GN stats accumulated from f32 values.
__global__ __launch_bounds__(256) void p2_k(char* __restrict__ ws,
                                            const float* __restrict__ ow_b)
{
  const int blk = blockIdx.x, t = threadIdx.x;
  __shared__ __attribute__((aligned(16))) __bf16 Al[2][64][72];
  __shared__ __attribute__((aligned(16))) __bf16 Bl[2][64][72];
  float* shf = (float*)(&Al[0][0][0]);

  const int lane = t & 63, wv = t >> 6;
  const int wm = (wv & 1) * 32, wn = (wv >> 1) * 32;
  const int fr = lane & 15, rbase = (lane >> 4) * 4;

  const int b = blk >> 6, t6 = blk & 63;
  const int mt = t6 >> 4, nt = t6 & 15;
  const int m0 = mt * 64, n0 = nt * 64;
  (void)nt;

  f32x4 acc[2][2]; ZERO_ACC(acc);
  gemm_acc((const __bf16*)(ws + OFF_T0) + (size_t)b * 65536,
           (const __bf16*)(ws + OFF_YT) + (size_t)b * 262144,
           256, m0, n0, Al, Bl, acc);

  const float* uv   = (const float*)(ws + OFF_UV);
  const float* cvec = (const float*)(ws + OFF_CVEC);
  const float* w2sp = (const float*)(ws + OFF_W2SP);
  const float s2v   = *(const float*)(ws + OFF_S2);
  float* SRAW = (float*)(ws + OFF_STATS);
  __bf16* zb = (__bf16*)(ws + OFF_ZB) + (size_t)b * 262144;

  float gs[2] = {0.f, 0.f}, gq[2] = {0.f, 0.f};
  int gidx[2];
  const float s1024 = 1.f / 1024.f;
#pragma unroll
  for (int i = 0; i < 2; ++i) {
    gidx[i] = (wm + i * 16 + rbase) >> 3;
#pragma unroll
    for (int r = 0; r < 4; ++r) {
      int m = m0 + wm + i * 16 + rbase + r;
      float coefm = uv[m] + cvec[b * 256 + m] * s1024;
      float qm = s2v * coefm + ow_b[m];
#pragma unroll
      for (int j = 0; j < 2; ++j) {
        int n = n0 + wn + j * 16 + fr;
        float w2n = w2sp[b * 1024 + n] + w2sp[4096 + b * 1024 + n];
        float v = acc[i][j][r] * s1024 + coefm * w2n + qm;
        zb[(size_t)m * 1024 + n] = (__bf16)v;
        gs[i] += v;
        gq[i] += v * v;
      }
    }
  }
  __syncthreads();
  if (t < 16) shf[t] = 0.f;
  __syncthreads();
#pragma unroll
  for (int i = 0; i < 2; ++i) {
    atomicAdd(&shf[gidx[i] * 2], gs[i]);
    atomicAdd(&shf[gidx[i] * 2 + 1], gq[i]);
  }
  __syncthreads();
  if (t < 16) {
    int g = mt * 8 + (t >> 1);
    atomicAdd(&SRAW[(b * 32 + g) * 2 + (t & 1)], shf[t]);
  }
}

// ---------------- fused GN + residual scatter (bf16 sources) ----------------
__device__ __forceinline__ float4 b2f4(const __bf16* p)
{
  bf16x4v v = *(const bf16x4v*)p;
  return (float4){(float)v[0], (float)v[1], (float)v[2], (float)v[3]};
}
__device__ __forceinline__ float4 gmix(float4 bz, float4 zz, float a, float c)
{
  float4 r;
  r.x = bz.x + zz.x * a + c;
  r.y = bz.y + zz.y * a + c;
  r.z = bz.z + zz.z * a + c;
  r.w = bz.w + zz.w * a + c;
  return r;
}
__device__ __forceinline__ float max4(float4 v)
{ return fmaxf(fmaxf(v.x, v.y), fmaxf(v.z, v.w)); }

// raw (sum, sumsq) -> (a = inv*gamma, c0 = beta - mean*a)
__device__ __forceinline__ void gn_coeff(const float2* __restrict__ ST,
                                         const float* __restrict__ gamma,
                                         const float* __restrict__ beta,
                                         int b, int ch, float& a, float& c0)
{
  float2 sq = ST[b * 32 + (ch >> 3)];
  float mean = sq.x * (1.0f / 8192.0f);
  float var  = sq.y * (1.0f / 8192.0f) - mean * mean;
  float inv  = rsqrtf(var + 1e-5f);
  a  = inv * gamma[ch];
  c0 = beta[ch] - mean * a;
}

__global__ __launch_bounds__(256) void scat_k(
    const char* __restrict__ ws,
    const float* __restrict__ f0, const float* __restrict__ f1,
    const float* __restrict__ f2, const float* __restrict__ f3,
    const float* __restrict__ f4,
    const float* __restrict__ gamma, const float* __restrict__ beta,
    float* __restrict__ out)
{
  const __bf16* ZB  = (const __bf16*)(ws + OFF_ZB);
  const __bf16* BSF = (const __bf16*)(ws + OFF_BSFB);
  const float2* ST = (const float2*)(ws + OFF_STATS);
  const int i4 = blockIdx.x * 256 + threadIdx.x;

  if (i4 < 4194304) {                       // f0: 128x128, upsample x4
    const int l = i4 << 2;
    const int x = l & 127, yy = (l >> 7) & 127, nc = l >> 14;
    const int ch = nc & 255, b = nc >> 8;
    float a, c0; gn_coeff(ST, gamma, beta, b, ch, a, c0);
    size_t base = (size_t)nc * 1024 + ((yy >> 2) << 5) + (x >> 2);
    float v = (float)BSF[base] + (float)ZB[base] * a + c0;
    float4 f = ((const float4*)f0)[i4];
    float4 o; o.x = f.x + v; o.y = f.y + v; o.z = f.z + v; o.w = f.w + v;
    ((float4*)out)[i4] = o;
  } else if (i4 < 5242880) {                // f1: 64x64, upsample x2
    const int l4 = i4 - 4194304;
    const int l = l4 << 2;
    const int x = l & 63, yy = (l >> 6) & 63, nc = l >> 12;
    const int ch = nc & 255, b = nc >> 8;
    float a, c0; gn_coeff(ST, gamma, beta, b, ch, a, c0);
    size_t base = (size_t)nc * 1024 + ((yy >> 1) << 5) + (x >> 1);
    float v0 = (float)BSF[base] + (float)ZB[base] * a + c0;
    float v1 = (float)BSF[base + 1] + (float)ZB[base + 1] * a + c0;
    float4 f = ((const float4*)f1)[l4];
    float4 o; o.x = f.x + v0; o.y = f.y + v0; o.z = f.z + v1; o.w = f.w + v1;
    ((float4*)out)[i4] = o;
  } else if (i4 < 5505024) {                // f2: 32x32, identity
    const int l4 = i4 - 5242880;
    const int l = l4 << 2;
    const int nc = l >> 10, e = l & 1023;
    const int ch = nc & 255, b = nc >> 8;
    float a, c0; gn_coeff(ST, gamma, beta, b, ch, a, c0);
    size_t base = (size_t)nc * 1024 + e;
    float4 z4 = b2f4(&ZB[base]);
    float4 b4 = b2f4(&BSF[base]);
    float4 v = gmix(b4, z4, a, c0);
    float4 f = ((const float4*)f2)[l4];
    float4 o; o.x = f.x + v.x; o.y = f.y + v.y; o.z = f.z + v.z; o.w = f.w + v.w;
    ((float4*)out)[i4] = o;
  } else if (i4 < 5570560) {                // f3: 16x16, maxpool 2x2
    const int l4 = i4 - 5505024;
    const int l = l4 << 2;
    const int x = l & 15, yy = (l >> 4) & 15, nc = l >> 8;
    const int ch = nc & 255, b = nc >> 8;
    float a, c0; gn_coeff(ST, gamma, beta, b, ch, a, c0);
    size_t base = (size_t)nc * 1024;
    const int p0 = (yy * 2) * 32 + (x * 2);
    float4 r0a = gmix(b2f4(&BSF[base + p0]),      b2f4(&ZB[base + p0]),      a, c0);
    float4 r0b = gmix(b2f4(&BSF[base + p0 + 4]),  b2f4(&ZB[base + p0 + 4]),  a, c0);
    float4 r1a = gmix(b2f4(&BSF[base + p0 + 32]), b2f4(&ZB[base + p0 + 32]), a, c0);
    float4 r1b = gmix(b2f4(&BSF[base + p0 + 36]), b2f4(&ZB[base + p0 + 36]), a, c0);
    float4 f = ((const float4*)f3)[l4];
    float4 o;
    o.x = f.x + fmaxf(fmaxf(r0a.x, r0a.y), fmaxf(r1a.x, r1a.y));
    o.y = f.y + fmaxf(fmaxf(r0a.z, r0a.w), fmaxf(r1a.z, r1a.w));
    o.z = f.z + fmaxf(fmaxf(r0b.x, r0b.y), fmaxf(r1b.x, r1b.y));
    o.w = f.w + fmaxf(fmaxf(r0b.z, r0b.w), fmaxf(r1b.z, r1b.w));
    ((float4*)out)[i4] = o;
  } else {                                   // f4: 8x8, maxpool 4x4
    const int l4 = i4 - 5570560;
    const int l = l4 << 2;
    const int x = l & 7, yy = (l >> 3) & 7, nc = l >> 6;
    const int ch = nc & 255, b = nc >> 8;
    float a, c0; gn_coeff(ST, gamma, beta, b, ch, a, c0);
    size_t base = (size_t)nc * 1024;
    float4 mx = {-3.4e38f, -3.4e38f, -3.4e38f, -3.4e38f};
#pragma unroll
    for (int r = 0; r < 4; ++r) {
      size_t rb = base + (size_t)(yy * 4 + r) * 32 + x * 4;
      float4 q0 = gmix(b2f4(&BSF[rb]),      b2f4(&ZB[rb]),      a, c0);
      float4 q1 = gmix(b2f4(&BSF[rb + 4]),  b2f4(&ZB[rb + 4]),  a, c0);
      float4 q2 = gmix(b2f4(&BSF[rb + 8]),  b2f4(&ZB[rb + 8]),  a, c0);
      float4 q3 = gmix(b2f4(&BSF[rb + 12]), b2f4(&ZB[rb + 12]), a, c0);
      mx.x = fmaxf(mx.x, max4(q0));
      mx.y = fmaxf(mx.y, max4(q1));
      mx.z = fmaxf(mx.z, max4(q2));
      mx.w = fmaxf(mx.w, max4(q3));
    }
    float4 f = ((const float4*)f4)[l4];
    float4 o; o.x = f.x + mx.x; o.y = f.y + mx.y; o.z = f.z + mx.z; o.w = f.w + mx.w;
    ((float4*)out)[i4] = o;
  }
}

// ---------------------------------------------------------------------------
extern "C" void kernel_launch(void* const* d_in, const int* in_sizes, int n_in,
                              void* d_out, int out_size, void* d_ws, size_t ws_size,
                              hipStream_t stream)
{
  (void)in_sizes; (void)n_in; (void)out_size; (void)ws_size;
  const float* f0   = (const float*)d_in[0];
  const float* f1   = (const float*)d_in[1];
  const float* f2   = (const float*)d_in[2];
  const float* f3   = (const float*)d_in[3];
  const float* f4   = (const float*)d_in[4];
  const float* g_w  = (const float*)d_in[5];
  const float* g_b  = (const float*)d_in[6];
  const float* th_w = (const float*)d_in[7];
  const float* th_b = (const float*)d_in[8];
  const float* ph_w = (const float*)d_in[9];
  const float* ph_b = (const float*)d_in[10];
  const float* ow_w = (const float*)d_in[11];
  const float* ow_b = (const float*)d_in[12];
  const float* gn_g = (const float*)d_in[13];
  const float* gn_b = (const float*)d_in[14];
  char* ws = (char*)d_ws;

  // 1) aux (blocks 0-77) + gather (blocks 78-1101)
  prep_k<<<1102, 256, 0, stream>>>(f0, f1, f2, f3, f4,
                                   g_w, ph_w, th_w, ow_w,
                                   g_b, ph_b, th_b, ws);
  // 2) S (hi/lo) ; U+UT ; V ; r ; w2sp parts
  p0_k<<<129, 256, 0, stream>>>(ws);
  // 3) T0' ; Yt(+v2 fold, own region) ; cvec
  p1_k<<<336, 256, 0, stream>>>(ws);
  // 4) z (bf16) + GN raw stats
  p2_k<<<256, 256, 0, stream>>>(ws, ow_b);
  // 5) fused GN-normalize + residual scatter (bf16 sources)
  scat_k<<<21824, 256, 0, stream>>>(ws, f0, f1, f2, f3, f4, gn_g, gn_b,
                                    (float*)d_out);
}